// Round 11
// baseline (596.339 us; speedup 1.0000x reference)
//
#include <hip/hip_runtime.h>
#include <math.h>

#define N_NODES 16000
#define N_EDGES 256000
#define EPE (N_EDGES + N_NODES)
#define DIN 1280
#define HID 256
#define HEADS 8
#define CPH 32
#define NG 32
#define NO 64
#define EPSC 1e-5f
#define SPAD 40     // GEMM LDS row stride (bf16): 80 B, 16B-aligned

typedef __bf16 bf16;
typedef __attribute__((ext_vector_type(8))) __bf16 bf16x8;
typedef __attribute__((ext_vector_type(4))) float floatx4;

__device__ __forceinline__ float lrelu(float v) { return v > 0.f ? v : 0.2f * v; }
__device__ __forceinline__ float bflo(unsigned int u) { return __uint_as_float(u << 16); }
__device__ __forceinline__ float bfhi(unsigned int u) { return __uint_as_float(u & 0xffff0000u); }
__device__ __forceinline__ unsigned int bfpack(float x, float y) {
    bf16 b0 = (bf16)x, b1 = (bf16)y;
    return ((unsigned int)*(unsigned short*)&b0) | (((unsigned int)*(unsigned short*)&b1) << 16);
}

// LDS-only barrier (no vmcnt drain): safe in loops with no global stores.
__device__ __forceinline__ void barrier_lds() {
    asm volatile("s_waitcnt lgkmcnt(0)" ::: "memory");
    __builtin_amdgcn_s_barrier();
}

// ---------- weight transpose/convert ----------
__global__ void wconv_gen(const float* __restrict__ W, bf16* __restrict__ Wt, int K, int total) {
    int idx = blockIdx.x * 256 + threadIdx.x;
    if (idx >= total) return;
    int per = K * HID;
    int l = idx / per, rem = idx - l * per;
    int n = rem / K, k = rem - n * K;
    Wt[idx] = (bf16)W[(size_t)l * per + (size_t)k * HID + n];
}

__global__ void wconv_pair(const float* __restrict__ Wl, const float* __restrict__ Wr,
                           bf16* __restrict__ Wt) {
    int idx = blockIdx.x * 256 + threadIdx.x;
    int n = idx >> 8, k = idx & 255;
    float v = (n < 256) ? Wl[(size_t)k * HID + n] : Wr[(size_t)k * HID + (n - 256)];
    Wt[idx] = (bf16)v;
}

// ---------- MFMA GEMM (bf16), 128x128 tile, 4-deep register pipeline ----------
// mode 0: +bias (bias2 for cols >= HID)
// mode 2: +bias,relu,bn,leaky AND atomicAdd block stats (sum,sumsq) into stat[0..1]
// mode 3: residual+LN: out = lrelu( (h-mu)*rs*g + b + (acc+bias) ), h reloaded from A
__global__ __launch_bounds__(256) void gemm128(
    const bf16* __restrict__ A, const bf16* __restrict__ Bt,
    const float* __restrict__ bias, const float* __restrict__ bias2,
    bf16* __restrict__ C, int K, int ldc, int mode,
    const float* __restrict__ g, const float* __restrict__ be,
    float* __restrict__ stat)
{
    __shared__ __align__(16) bf16 As[2][128 * SPAD];
    __shared__ __align__(16) bf16 Bs[2][128 * SPAD];
    const int tid = threadIdx.x;
    const int bm = blockIdx.y * 128, bn = blockIdx.x * 128;
    const int w = tid >> 6, lane = tid & 63;
    const int wm = (w & 1) * 64, wn = (w >> 1) * 64;
    const int lrow = lane & 15, lk8 = (lane >> 4) * 8;

    floatx4 acc[4][4];
#pragma unroll
    for (int i = 0; i < 4; i++)
#pragma unroll
        for (int j = 0; j < 4; j++) acc[i][j] = (floatx4){0.f, 0.f, 0.f, 0.f};

    const int r2 = tid >> 1, c2 = tid & 1;
    const bf16* gA = A + (size_t)(bm + r2) * K + c2 * 16;
    const bf16* gB = Bt + (size_t)(bn + r2) * K + c2 * 16;
    bf16* sA = &As[0][r2 * SPAD + c2 * 16];
    bf16* sB = &Bs[0][r2 * SPAD + c2 * 16];

    const int nk = K >> 5;   // 8
    bf16x8 a[4][2], b[4][2];
#pragma unroll
    for (int u = 0; u < 4; u++) {
        const bf16* pa = gA + u * 32;
        a[u][0] = *(const bf16x8*)(pa + 0);
        a[u][1] = *(const bf16x8*)(pa + 8);
        const bf16* pb = gB + u * 32;
        b[u][0] = *(const bf16x8*)(pb + 0);
        b[u][1] = *(const bf16x8*)(pb + 8);
    }

    for (int it0 = 0; it0 < nk; it0 += 4) {
#pragma unroll
        for (int u = 0; u < 4; u++) {
            const int it = it0 + u;
            const int p = u & 1;
            const int po = p * 128 * SPAD;
            *(bf16x8*)(sA + po + 0) = a[u][0];
            *(bf16x8*)(sA + po + 8) = a[u][1];
            *(bf16x8*)(sB + po + 0) = b[u][0];
            *(bf16x8*)(sB + po + 8) = b[u][1];
            barrier_lds();
            if (it + 4 < nk) {
                const bf16* pa = gA + (it + 4) * 32;
                a[u][0] = *(const bf16x8*)(pa + 0);
                a[u][1] = *(const bf16x8*)(pa + 8);
                const bf16* pb = gB + (it + 4) * 32;
                b[u][0] = *(const bf16x8*)(pb + 0);
                b[u][1] = *(const bf16x8*)(pb + 8);
            }
            bf16x8 af[4], bfr[4];
#pragma unroll
            for (int i = 0; i < 4; i++) af[i] = *(const bf16x8*)&As[p][(wm + 16 * i + lrow) * SPAD + lk8];
#pragma unroll
            for (int j = 0; j < 4; j++) bfr[j] = *(const bf16x8*)&Bs[p][(wn + 16 * j + lrow) * SPAD + lk8];
#pragma unroll
            for (int i = 0; i < 4; i++)
#pragma unroll
                for (int j = 0; j < 4; j++)
                    acc[i][j] = __builtin_amdgcn_mfma_f32_16x16x32_bf16(af[i], bfr[j], acc[i][j], 0, 0, 0);
            barrier_lds();
        }
    }

    const float inv = rsqrtf(1.f + EPSC);
    float mu = 0.f, rs = 0.f;
    if (mode == 3) {
        const float inv_n = 1.f / (float)((size_t)N_NODES * HID);
        mu = stat[0] * inv_n;
        float var = stat[1] * inv_n - mu * mu;
        rs = 1.f / (sqrtf(fmaxf(var, 0.f)) + EPSC);
    }
    float sz = 0.f, sq = 0.f;
#pragma unroll
    for (int j = 0; j < 4; j++) {
        int col = bn + wn + 16 * j + lrow;
        float bcol = (col < HID) ? bias[col] : bias2[col - HID];
        float gc = (mode >= 2) ? g[col] : 0.f;
        float bec = (mode >= 2) ? be[col] : 0.f;
#pragma unroll
        for (int i = 0; i < 4; i++) {
            int row0 = bm + wm + 16 * i + (lane >> 4) * 4;
#pragma unroll
            for (int r = 0; r < 4; r++) {
                float z = acc[i][j][r] + bcol;
                if (mode == 2) {
                    z = fmaxf(z, 0.f) * (gc * inv) + bec;
                    z = lrelu(z);
                    sz += z; sq += z * z;
                } else if (mode == 3) {
                    float h = (float)A[(size_t)(row0 + r) * K + col];
                    z = (h - mu) * rs * gc + bec + z;
                    z = lrelu(z);
                }
                C[(size_t)(row0 + r) * ldc + col] = (bf16)z;
            }
        }
    }
    if (mode == 2) {
        for (int o = 32; o > 0; o >>= 1) { sz += __shfl_down(sz, o); sq += __shfl_down(sq, o); }
        __syncthreads();                     // mainloop LDS readers done
        float* rs_ = (float*)&As[0][0];
        float* rq_ = (float*)&Bs[0][0];
        if (lane == 0) { rs_[w] = sz; rq_[w] = sq; }
        __syncthreads();
        if (tid == 0) {
            atomicAdd(&stat[0], rs_[0] + rs_[1] + rs_[2] + rs_[3]);
            atomicAdd(&stat[1], rq_[0] + rq_[1] + rq_[2] + rq_[3]);
        }
    }
}

// ---------- MFMA GEMM (fp32 A), 128x128 tile, depth-4 pipeline (champion, CLOSED) ----------
__global__ __launch_bounds__(256, 1) void gemm_f32A(
    const float* __restrict__ A, const bf16* __restrict__ Bt,
    const float* __restrict__ bias, bf16* __restrict__ C, int K,
    const float* __restrict__ g, const float* __restrict__ be)
{
    __shared__ __align__(16) bf16 As[2][128 * SPAD];
    __shared__ __align__(16) bf16 Bs[2][128 * SPAD];
    const int tid = threadIdx.x;
    const int bm = blockIdx.y * 128, bn = blockIdx.x * 128;
    const int w = tid >> 6, lane = tid & 63;
    const int wm = (w & 1) * 64, wn = (w >> 1) * 64;
    const int lrow = lane & 15, lk8 = (lane >> 4) * 8;

    floatx4 acc[4][4];
#pragma unroll
    for (int i = 0; i < 4; i++)
#pragma unroll
        for (int j = 0; j < 4; j++) acc[i][j] = (floatx4){0.f, 0.f, 0.f, 0.f};

    const int r2 = tid >> 1, c2 = tid & 1;
    const float* gA = A + (size_t)(bm + r2) * K + c2 * 16;
    const bf16* gB = Bt + (size_t)(bn + r2) * K + c2 * 16;
    bf16* sA = &As[0][r2 * SPAD + c2 * 16];
    bf16* sB = &Bs[0][r2 * SPAD + c2 * 16];

    const int nk = K >> 5;   // 40
    float4 a[4][4];
    bf16x8 b[4][2];
#pragma unroll
    for (int u = 0; u < 4; u++) {
        const float* pa = gA + u * 32;
        a[u][0] = *(const float4*)(pa + 0);
        a[u][1] = *(const float4*)(pa + 4);
        a[u][2] = *(const float4*)(pa + 8);
        a[u][3] = *(const float4*)(pa + 12);
        const bf16* pb = gB + u * 32;
        b[u][0] = *(const bf16x8*)(pb + 0);
        b[u][1] = *(const bf16x8*)(pb + 8);
    }

    for (int it0 = 0; it0 < nk; it0 += 4) {
#pragma unroll
        for (int u = 0; u < 4; u++) {
            const int it = it0 + u;
            const int p = u & 1;
            const int po = p * 128 * SPAD;
            bf16x8 h0, h1;
            h0[0] = (bf16)a[u][0].x; h0[1] = (bf16)a[u][0].y; h0[2] = (bf16)a[u][0].z; h0[3] = (bf16)a[u][0].w;
            h0[4] = (bf16)a[u][1].x; h0[5] = (bf16)a[u][1].y; h0[6] = (bf16)a[u][1].z; h0[7] = (bf16)a[u][1].w;
            h1[0] = (bf16)a[u][2].x; h1[1] = (bf16)a[u][2].y; h1[2] = (bf16)a[u][2].z; h1[3] = (bf16)a[u][2].w;
            h1[4] = (bf16)a[u][3].x; h1[5] = (bf16)a[u][3].y; h1[6] = (bf16)a[u][3].z; h1[7] = (bf16)a[u][3].w;
            *(bf16x8*)(sA + po + 0) = h0;
            *(bf16x8*)(sA + po + 8) = h1;
            *(bf16x8*)(sB + po + 0) = b[u][0];
            *(bf16x8*)(sB + po + 8) = b[u][1];
            barrier_lds();
            if (it + 4 < nk) {
                const float* pa = gA + (it + 4) * 32;
                a[u][0] = *(const float4*)(pa + 0);
                a[u][1] = *(const float4*)(pa + 4);
                a[u][2] = *(const float4*)(pa + 8);
                a[u][3] = *(const float4*)(pa + 12);
                const bf16* pb = gB + (it + 4) * 32;
                b[u][0] = *(const bf16x8*)(pb + 0);
                b[u][1] = *(const bf16x8*)(pb + 8);
            }
            bf16x8 af[4], bfr[4];
#pragma unroll
            for (int i = 0; i < 4; i++) af[i] = *(const bf16x8*)&As[p][(wm + 16 * i + lrow) * SPAD + lk8];
#pragma unroll
            for (int j = 0; j < 4; j++) bfr[j] = *(const bf16x8*)&Bs[p][(wn + 16 * j + lrow) * SPAD + lk8];
#pragma unroll
            for (int i = 0; i < 4; i++)
#pragma unroll
                for (int j = 0; j < 4; j++)
                    acc[i][j] = __builtin_amdgcn_mfma_f32_16x16x32_bf16(af[i], bfr[j], acc[i][j], 0, 0, 0);
            barrier_lds();
        }
    }

    const float inv = rsqrtf(1.f + EPSC);
#pragma unroll
    for (int j = 0; j < 4; j++) {
        int col = bn + wn + 16 * j + lrow;
        float bcol = bias[col];
        float gc = g[col] * inv;
        float bec = be[col];
#pragma unroll
        for (int i = 0; i < 4; i++) {
            int row0 = bm + wm + 16 * i + (lane >> 4) * 4;
#pragma unroll
            for (int r = 0; r < 4; r++) {
                float z = fmaxf(acc[i][j][r] + bcol, 0.f) * gc + bec;
                C[(size_t)(row0 + r) * HID + col] = (bf16)z;
            }
        }
    }
}

// ---------- CSR build ----------
__global__ void hist_kernel(const int* __restrict__ ei, int* __restrict__ cnt) {
    int e = blockIdx.x * 256 + threadIdx.x;
    if (e >= EPE) return;
    int d = (e < N_EDGES) ? ei[N_EDGES + e] : (e - N_EDGES);
    atomicAdd(&cnt[d], 1);
}

__global__ __launch_bounds__(1024) void scan_kernel(const int* __restrict__ cnt,
                                                    int* __restrict__ roff, int* __restrict__ cursor,
                                                    const int* __restrict__ batch,
                                                    int* __restrict__ gstart) {
    __shared__ int wsum[16];
    int t = threadIdx.x;
    int base = t * 16;
    int local[16]; int s = 0;
#pragma unroll
    for (int i = 0; i < 16; i++) {
        int idx = base + i;
        int v = (idx < N_NODES) ? cnt[idx] : 0;
        local[i] = s; s += v;
    }
    int lane = t & 63, wid = t >> 6;
    int incl = s;
    for (int o = 1; o < 64; o <<= 1) { int v = __shfl_up(incl, o); if (lane >= o) incl += v; }
    if (lane == 63) wsum[wid] = incl;
    __syncthreads();
    if (t == 0) { int a = 0; for (int k = 0; k < 16; k++) { int v = wsum[k]; wsum[k] = a; a += v; } }
    __syncthreads();
    int texcl = incl - s + wsum[wid];
#pragma unroll
    for (int i = 0; i < 16; i++) {
        int idx = base + i;
        if (idx < N_NODES) { int o = texcl + local[i]; roff[idx] = o; cursor[idx] = o; }
    }
    if (t == 1023) roff[N_NODES] = texcl + s;
    if (t <= NG) {
        int lo = 0, hi = N_NODES;
        while (lo < hi) { int mid = (lo + hi) >> 1; if (batch[mid] < t) lo = mid + 1; else hi = mid; }
        gstart[t] = lo;
    }
}

__global__ void scatter_kernel(const int* __restrict__ ei, int* __restrict__ cursor,
                               int* __restrict__ esrc) {
    int e = blockIdx.x * 256 + threadIdx.x;
    if (e >= EPE) return;
    int s, d;
    if (e < N_EDGES) { s = ei[e]; d = ei[N_EDGES + e]; }
    else { s = d = e - N_EDGES; }
    int pos = atomicAdd(&cursor[d], 1);
    esrc[pos] = s;
}

// ---------- wave-per-dst GATv2: 4 edges/iter ----------
__global__ __launch_bounds__(256) void gat_wave(
    const bf16* __restrict__ XLR, const int* __restrict__ roff, const int* __restrict__ esrc,
    const float* __restrict__ att, const float* __restrict__ gbias, bf16* __restrict__ out)
{
    const int wid = threadIdx.x >> 6;
    const int lane = threadIdx.x & 63;
    const int d = blockIdx.x * 4 + wid;
    const int beg = roff[d], end = roff[d + 1];
    const int c0 = lane * 4;

    const unsigned int* xru = (const unsigned int*)(XLR + (size_t)d * 512 + 256 + c0);
    const unsigned int xr01 = xru[0], xr23 = xru[1];
    const float xr0 = bflo(xr01), xr1 = bfhi(xr01), xr2 = bflo(xr23), xr3 = bfhi(xr23);
    const float at0 = att[c0], at1 = att[c0 + 1], at2 = att[c0 + 2], at3 = att[c0 + 3];

    float m = -INFINITY, s = 0.f;
    float a0 = 0.f, a1 = 0.f, a2 = 0.f, a3 = 0.f;

    int e = beg;
    for (; e + 3 < end; e += 4) {
        int s0 = esrc[e], s1 = esrc[e + 1], s2 = esrc[e + 2], s3 = esrc[e + 3];
        const unsigned int* q0 = (const unsigned int*)(XLR + (size_t)s0 * 512 + c0);
        const unsigned int* q1 = (const unsigned int*)(XLR + (size_t)s1 * 512 + c0);
        const unsigned int* q2 = (const unsigned int*)(XLR + (size_t)s2 * 512 + c0);
        const unsigned int* q3 = (const unsigned int*)(XLR + (size_t)s3 * 512 + c0);
        unsigned int u01 = q0[0], u23 = q0[1];
        unsigned int v01 = q1[0], v23 = q1[1];
        unsigned int w01 = q2[0], w23 = q2[1];
        unsigned int x01 = q3[0], x23 = q3[1];
        float x0 = bflo(u01), x1 = bfhi(u01), x2 = bflo(u23), x3 = bfhi(u23);
        float y0 = bflo(v01), y1 = bfhi(v01), y2 = bflo(v23), y3 = bfhi(v23);
        float z0 = bflo(w01), z1 = bfhi(w01), z2 = bflo(w23), z3 = bfhi(w23);
        float t0 = bflo(x01), t1 = bfhi(x01), t2 = bflo(x23), t3 = bfhi(x23);
        float p0 = lrelu(x0 + xr0) * at0 + lrelu(x1 + xr1) * at1
                 + lrelu(x2 + xr2) * at2 + lrelu(x3 + xr3) * at3;
        float p1 = lrelu(y0 + xr0) * at0 + lrelu(y1 + xr1) * at1
                 + lrelu(y2 + xr2) * at2 + lrelu(y3 + xr3) * at3;
        float p2 = lrelu(z0 + xr0) * at0 + lrelu(z1 + xr1) * at1
                 + lrelu(z2 + xr2) * at2 + lrelu(z3 + xr3) * at3;
        float p3 = lrelu(t0 + xr0) * at0 + lrelu(t1 + xr1) * at1
                 + lrelu(t2 + xr2) * at2 + lrelu(t3 + xr3) * at3;
        p0 += __shfl_xor(p0, 1);  p1 += __shfl_xor(p1, 1);
        p2 += __shfl_xor(p2, 1);  p3 += __shfl_xor(p3, 1);
        p0 += __shfl_xor(p0, 2);  p1 += __shfl_xor(p1, 2);
        p2 += __shfl_xor(p2, 2);  p3 += __shfl_xor(p3, 2);
        p0 += __shfl_xor(p0, 4);  p1 += __shfl_xor(p1, 4);
        p2 += __shfl_xor(p2, 4);  p3 += __shfl_xor(p3, 4);
        float mn = fmaxf(fmaxf(m, fmaxf(p0, p1)), fmaxf(p2, p3));
        float rsc = __expf(m - mn);              // first iter: exp(-inf)=0
        float w0 = __expf(p0 - mn);
        float w1 = __expf(p1 - mn);
        float w2 = __expf(p2 - mn);
        float w3 = __expf(p3 - mn);
        s = s * rsc + (w0 + w1) + (w2 + w3);
        a0 = a0 * rsc + (w0 * x0 + w1 * y0) + (w2 * z0 + w3 * t0);
        a1 = a1 * rsc + (w0 * x1 + w1 * y1) + (w2 * z1 + w3 * t1);
        a2 = a2 * rsc + (w0 * x2 + w1 * y2) + (w2 * z2 + w3 * t2);
        a3 = a3 * rsc + (w0 * x3 + w1 * y3) + (w2 * z3 + w3 * t3);
        m = mn;
    }
    for (; e < end; ++e) {                       // tail (0-3 edges)
        int s0 = esrc[e];
        const unsigned int* q0 = (const unsigned int*)(XLR + (size_t)s0 * 512 + c0);
        unsigned int u01 = q0[0], u23 = q0[1];
        float x0 = bflo(u01), x1 = bfhi(u01), x2 = bflo(u23), x3 = bfhi(u23);
        float p = lrelu(x0 + xr0) * at0 + lrelu(x1 + xr1) * at1
                + lrelu(x2 + xr2) * at2 + lrelu(x3 + xr3) * at3;
        p += __shfl_xor(p, 1);
        p += __shfl_xor(p, 2);
        p += __shfl_xor(p, 4);
        float mn = fmaxf(m, p);
        float rsc = __expf(m - mn);
        float wgt = __expf(p - mn);
        s = s * rsc + wgt;
        a0 = a0 * rsc + wgt * x0;
        a1 = a1 * rsc + wgt * x1;
        a2 = a2 * rsc + wgt * x2;
        a3 = a3 * rsc + wgt * x3;
        m = mn;
    }

    const float rinv = 1.f / (s + 1e-16f);
    float v0 = gbias[c0]     + a0 * rinv;
    float v1 = gbias[c0 + 1] + a1 * rinv;
    float v2 = gbias[c0 + 2] + a2 * rinv;
    float v3 = gbias[c0 + 3] + a3 * rinv;
    unsigned int* op = (unsigned int*)(out + (size_t)d * HID + c0);
    op[0] = bfpack(v0, v1);
    op[1] = bfpack(v2, v3);
}

// ---------- wave-per-dst GIN gather (4 gathers in flight) + zero stat ----------
__global__ __launch_bounds__(256) void gin_wave(
    const bf16* __restrict__ H, const int* __restrict__ roff,
    const int* __restrict__ esrc, bf16* __restrict__ U, float* __restrict__ stat)
{
    if (blockIdx.x == 0 && threadIdx.x == 0) { stat[0] = 0.f; stat[1] = 0.f; }
    const int wid = threadIdx.x >> 6;
    const int lane = threadIdx.x & 63;
    const int d = blockIdx.x * 4 + wid;
    const int beg = roff[d], end = roff[d + 1];
    const int c0 = lane * 4;

    float a0 = 0.f, a1 = 0.f, a2 = 0.f, a3 = 0.f;
    int e = beg;
    for (; e + 3 < end; e += 4) {
        int s0 = esrc[e], s1 = esrc[e + 1], s2 = esrc[e + 2], s3 = esrc[e + 3];
        const unsigned int* p0 = (const unsigned int*)(H + (size_t)s0 * HID + c0);
        const unsigned int* p1 = (const unsigned int*)(H + (size_t)s1 * HID + c0);
        const unsigned int* p2 = (const unsigned int*)(H + (size_t)s2 * HID + c0);
        const unsigned int* p3 = (const unsigned int*)(H + (size_t)s3 * HID + c0);
        unsigned int u01 = p0[0], u23 = p0[1];
        unsigned int v01 = p1[0], v23 = p1[1];
        unsigned int w01 = p2[0], w23 = p2[1];
        unsigned int x01 = p3[0], x23 = p3[1];
        a0 += (bflo(u01) + bflo(v01)) + (bflo(w01) + bflo(x01));
        a1 += (bfhi(u01) + bfhi(v01)) + (bfhi(w01) + bfhi(x01));
        a2 += (bflo(u23) + bflo(v23)) + (bflo(w23) + bflo(x23));
        a3 += (bfhi(u23) + bfhi(v23)) + (bfhi(w23) + bfhi(x23));
    }
    for (; e < end; ++e) {
        const unsigned int* p0 = (const unsigned int*)(H + (size_t)esrc[e] * HID + c0);
        unsigned int u01 = p0[0], u23 = p0[1];
        a0 += bflo(u01); a1 += bfhi(u01); a2 += bflo(u23); a3 += bfhi(u23);
    }
    unsigned int* up = (unsigned int*)(U + (size_t)d * HID + c0);
    up[0] = bfpack(a0, a1);
    up[1] = bfpack(a2, a3);
}

// ---------- pooling ----------
__global__ __launch_bounds__(256) void pool_gate_kernel(const bf16* __restrict__ t,
    const float* __restrict__ W2, const float* __restrict__ b2, float* __restrict__ gate)
{
    int n = blockIdx.x * 4 + (threadIdx.x >> 6);
    int lane = threadIdx.x & 63;
    const bf16* p = t + (size_t)n * HID + lane * 4;
    float4 w = *(const float4*)(W2 + lane * 4);
    float s = tanhf((float)p[0]) * w.x + tanhf((float)p[1]) * w.y
            + tanhf((float)p[2]) * w.z + tanhf((float)p[3]) * w.w;
    for (int o = 32; o > 0; o >>= 1) s += __shfl_down(s, o);
    if (lane == 0) gate[n] = s + b2[0];
}

__global__ __launch_bounds__(256) void pool_stats_kernel(
    float* __restrict__ gate, const int* __restrict__ gstart)
{
    int g = blockIdx.x, t = threadIdx.x;
    int lo = gstart[g], hi = gstart[g + 1];
    __shared__ float red[256];
    float m = -INFINITY;
    for (int n = lo + t; n < hi; n += 256) m = fmaxf(m, gate[n]);
    red[t] = m; __syncthreads();
    for (int st = 128; st > 0; st >>= 1) { if (t < st) red[t] = fmaxf(red[t], red[t + st]); __syncthreads(); }
    m = red[0]; __syncthreads();
    float s = 0.f;
    for (int n = lo + t; n < hi; n += 256) s += __expf(gate[n] - m);
    red[t] = s; __syncthreads();
    for (int st = 128; st > 0; st >>= 1) { if (t < st) red[t] += red[t + st]; __syncthreads(); }
    float sinv = 1.f / (red[0] + 1e-16f);
    for (int n = lo + t; n < hi; n += 256) gate[n] = __expf(gate[n] - m) * sinv;
}

__global__ __launch_bounds__(256) void emb_accum_kernel(
    const float* __restrict__ a, const int* __restrict__ batch,
    const bf16* __restrict__ h, float* __restrict__ emb)
{
    int n0 = blockIdx.x * 32, t = threadIdx.x;
    int cur = batch[n0]; float acc = 0.f;
    for (int j = 0; j < 32; j++) {
        int n = n0 + j;
        int b = batch[n];
        if (b != cur) { atomicAdd(&emb[cur * HID + t], acc); cur = b; acc = 0.f; }
        acc += a[n] * (float)h[(size_t)n * HID + t];
    }
    atomicAdd(&emb[cur * HID + t], acc);
}

// ---------- label heads: ONE block per label, W1 read ONCE (was 8x) ----------
// Thread k owns output channel k; all 32 graph embeddings staged in LDS (32 KB);
// acc[32] in registers. Inner loop: 4 coalesced W1 loads + 32 broadcast
// ds_read_b128 + 128 FMA per d4. Epilogue: silu/bn/W2-dot, per-wave shuffle
// reduce + 4-partial combine. All fp32 (identical numerics to previous version).
__global__ __launch_bounds__(256) void heads_kernel(
    const float* __restrict__ emb, const float* __restrict__ W1, const float* __restrict__ b1,
    const float* __restrict__ hg, const float* __restrict__ hbe, const float* __restrict__ W2,
    const float* __restrict__ b2, float* __restrict__ out)
{
    const int o = blockIdx.x;
    const int k = threadIdx.x;
    __shared__ float se[NG][HID];       // 32 KB
    __shared__ float part[NG][4];
#pragma unroll
    for (int i = 0; i < 8; i++)
        ((float4*)&se[0][0])[k + i * 256] = ((const float4*)emb)[k + i * 256];
    __syncthreads();

    const float* w1p = W1 + (size_t)o * HID * HID + k;
    const float zb = b1[o * HID + k];
    float acc[NG];
#pragma unroll
    for (int j = 0; j < NG; j++) acc[j] = zb;

    for (int d4 = 0; d4 < HID / 4; d4++) {
        float w0 = w1p[(size_t)(d4 * 4 + 0) * HID];
        float w1v = w1p[(size_t)(d4 * 4 + 1) * HID];
        float w2v = w1p[(size_t)(d4 * 4 + 2) * HID];
        float w3v = w1p[(size_t)(d4 * 4 + 3) * HID];
#pragma unroll
        for (int j = 0; j < NG; j++) {
            float4 s4 = *(const float4*)&se[j][d4 * 4];
            acc[j] = fmaf(s4.x, w0, acc[j]);
            acc[j] = fmaf(s4.y, w1v, acc[j]);
            acc[j] = fmaf(s4.z, w2v, acc[j]);
            acc[j] = fmaf(s4.w, w3v, acc[j]);
        }
    }

    const float gk = hg[o * HID + k] * rsqrtf(1.f + EPSC);
    const float bek = hbe[o * HID + k];
    const float w2 = W2[o * HID + k];
    const int wid = k >> 6, lane = k & 63;
#pragma unroll
    for (int j = 0; j < NG; j++) {
        float z = acc[j];
        float sil = z / (1.f + expf(-z));
        float v = (sil * gk + bek) * w2;
        for (int off = 32; off > 0; off >>= 1) v += __shfl_down(v, off);
        if (lane == 0) part[j][wid] = v;
    }
    __syncthreads();
    if (k < NG)
        out[k * NO + o] = part[k][0] + part[k][1] + part[k][2] + part[k][3] + b2[o];
}

extern "C" void kernel_launch(void* const* d_in, const int* in_sizes, int n_in,
                              void* d_out, int out_size, void* d_ws, size_t ws_size,
                              hipStream_t stream) {
    const float* x        = (const float*)d_in[0];
    const int*   ei       = (const int*)  d_in[1];
    const int*   batch    = (const int*)  d_in[2];
    const float* fp_W     = (const float*)d_in[3];
    const float* fp_b     = (const float*)d_in[4];
    const float* fp_g     = (const float*)d_in[5];
    const float* fp_be    = (const float*)d_in[6];
    const float* gat_Wl   = (const float*)d_in[7];
    const float* gat_bl   = (const float*)d_in[8];
    const float* gat_Wr   = (const float*)d_in[9];
    const float* gat_br   = (const float*)d_in[10];
    const float* gat_att  = (const float*)d_in[11];
    const float* gat_bias = (const float*)d_in[12];
    const float* gin_W    = (const float*)d_in[13];
    const float* gin_b    = (const float*)d_in[14];
    const float* gin_g    = (const float*)d_in[15];
    const float* gin_be   = (const float*)d_in[16];
    const float* ln_g     = (const float*)d_in[17];
    const float* ln_b     = (const float*)d_in[18];
    const float* res_W    = (const float*)d_in[19];
    const float* res_b    = (const float*)d_in[20];
    const float* pool_W1  = (const float*)d_in[21];
    const float* pool_b1  = (const float*)d_in[22];
    const float* pool_W2  = (const float*)d_in[23];
    const float* pool_b2  = (const float*)d_in[24];
    const float* head_W1  = (const float*)d_in[25];
    const float* head_b1  = (const float*)d_in[26];
    const float* head_g   = (const float*)d_in[27];
    const float* head_be  = (const float*)d_in[28];
    const float* head_W2  = (const float*)d_in[29];
    const float* head_b2  = (const float*)d_in[30];
    float* out = (float*)d_out;

    char* base = (char*)d_ws;
    size_t off = 0;
    auto alloc = [&](size_t bytes) -> char* {
        char* p = base + off; off += (bytes + 255) & ~(size_t)255; return p;
    };
    int*   esrc   = (int*)  alloc((size_t)EPE * 4);
    int*   cnt    = (int*)  alloc((size_t)N_NODES * 4);
    int*   roff   = (int*)  alloc((size_t)(N_NODES + 1) * 4);
    int*   cursor = (int*)  alloc((size_t)N_NODES * 4);
    float* gate   = (float*)alloc((size_t)N_NODES * 4);
    int*   gstart = (int*)  alloc((NG + 1) * 4);
    float* emb    = (float*)alloc(NG * HID * 4);
    float* stat   = (float*)alloc(8);
    bf16*  Hb0    = (bf16*) alloc((size_t)N_NODES * HID * 2);
    bf16*  Hb1    = (bf16*) alloc((size_t)N_NODES * HID * 2);
    bf16*  XLR    = (bf16*) alloc((size_t)N_NODES * 512 * 2);
    bf16*  fpWt   = (bf16*) alloc((size_t)DIN * HID * 2);
    bf16*  wlrT0  = (bf16*) alloc((size_t)512 * HID * 2);
    bf16*  wlrT1  = (bf16*) alloc((size_t)512 * HID * 2);
    bf16*  gwT    = (bf16*) alloc((size_t)2 * HID * HID * 2);
    bf16*  rwT    = (bf16*) alloc((size_t)2 * HID * HID * 2);
    bf16*  pwT    = (bf16*) alloc((size_t)HID * HID * 2);
    bf16*  Ub     = XLR;
    bf16*  wlrT[2] = { wlrT0, wlrT1 };

    // ---- weight conversions (small concurrent kernels) ----
    wconv_gen<<<(DIN * HID + 255) / 256, 256, 0, stream>>>(fp_W, fpWt, DIN, DIN * HID);
    wconv_pair<<<512, 256, 0, stream>>>(gat_Wl, gat_Wr, wlrT0);
    wconv_pair<<<512, 256, 0, stream>>>(gat_Wl + HID * HID, gat_Wr + HID * HID, wlrT1);
    wconv_gen<<<512, 256, 0, stream>>>(gin_W, gwT, HID, 2 * HID * HID);
    wconv_gen<<<512, 256, 0, stream>>>(res_W, rwT, HID, 2 * HID * HID);
    wconv_gen<<<256, 256, 0, stream>>>(pool_W1, pwT, HID, HID * HID);

    // ---- CSR build (+ graph boundaries fused into scan) ----
    hipMemsetAsync(cnt, 0, N_NODES * sizeof(int), stream);
    hist_kernel<<<(EPE + 255) / 256, 256, 0, stream>>>(ei, cnt);
    scan_kernel<<<1, 1024, 0, stream>>>(cnt, roff, cursor, batch, gstart);
    scatter_kernel<<<(EPE + 255) / 256, 256, 0, stream>>>(ei, cursor, esrc);

    // ---- feature projection (128x128 tiles, depth-4, champion config) ----
    dim3 gridF(2, 125);
    dim3 g128_256(2, 125);       // 128x128 tiles, 256 cols
    dim3 g128_512(4, 125);       // 128x128 tiles, 512 cols
    gemm_f32A<<<gridF, 256, 0, stream>>>(x, fpWt, fp_b, Hb0, DIN, fp_g, fp_be);

    bf16* hcur = Hb0;
    bf16* hoth = Hb1;
    for (int i = 0; i < 2; i++) {
        // xl|xr
        gemm128<<<g128_512, 256, 0, stream>>>(hcur, wlrT[i], gat_bl + i * HID, gat_br + i * HID,
                                              XLR, HID, 512, 0, nullptr, nullptr, nullptr);
        // GAT -> hoth (wave-per-dst, 4 edges/iter)
        gat_wave<<<N_NODES / 4, 256, 0, stream>>>(XLR, roff, esrc, gat_att + i * HEADS * CPH,
                                                  gat_bias + i * HID, hoth);
        // GIN aggregate -> Ub (wave-per-dst, 4 gathers/iter), zeroes stat
        gin_wave<<<N_NODES / 4, 256, 0, stream>>>(hoth, roff, esrc, Ub, stat);
        // h_gin = leaky(BN(relu(u@W+b))) -> hcur, stats atomically into stat
        gemm128<<<g128_256, 256, 0, stream>>>(Ub, gwT + (size_t)i * HID * HID, gin_b + i * HID,
                                              nullptr, hcur, HID, HID, 2,
                                              gin_g + i * HID, gin_be + i * HID, stat);
        // h = leaky(LN(h_gin) + h_gin@res_W + res_b) -> hoth
        gemm128<<<g128_256, 256, 0, stream>>>(hcur, rwT + (size_t)i * HID * HID, res_b + i * HID,
                                              nullptr, hoth, HID, HID, 3,
                                              ln_g + i * HID, ln_b + i * HID, stat);
        bf16* tmp = hcur; hcur = hoth; hoth = tmp;
    }

    // ---- global attention pooling ----
    gemm128<<<g128_256, 256, 0, stream>>>(hcur, pwT, pool_b1, nullptr, hoth, HID, HID, 0,
                                          nullptr, nullptr, nullptr);
    pool_gate_kernel<<<N_NODES / 4, 256, 0, stream>>>(hoth, pool_W2, pool_b2, gate);
    pool_stats_kernel<<<NG, 256, 0, stream>>>(gate, gstart);
    hipMemsetAsync(emb, 0, NG * HID * sizeof(float), stream);
    emb_accum_kernel<<<N_NODES / 32, 256, 0, stream>>>(gate, batch, hcur, emb);

    // ---- label heads (one block per label, W1 read once) ----
    heads_kernel<<<NO, 256, 0, stream>>>(emb, head_W1, head_b1, head_g, head_be,
                                         head_W2, head_b2, out);
}

// Round 12
// 537.907 us; speedup vs baseline: 1.1086x; 1.1086x over previous
//
#include <hip/hip_runtime.h>
#include <math.h>

#define N_NODES 16000
#define N_EDGES 256000
#define EPE (N_EDGES + N_NODES)
#define DIN 1280
#define HID 256
#define HEADS 8
#define CPH 32
#define NG 32
#define NO 64
#define EPSC 1e-5f
#define SPAD 40     // GEMM LDS row stride (bf16): 80 B, 16B-aligned

typedef __bf16 bf16;
typedef __attribute__((ext_vector_type(8))) __bf16 bf16x8;
typedef __attribute__((ext_vector_type(4))) float floatx4;

__device__ __forceinline__ float lrelu(float v) { return v > 0.f ? v : 0.2f * v; }
__device__ __forceinline__ float bflo(unsigned int u) { return __uint_as_float(u << 16); }
__device__ __forceinline__ float bfhi(unsigned int u) { return __uint_as_float(u & 0xffff0000u); }
__device__ __forceinline__ unsigned int bfpack(float x, float y) {
    bf16 b0 = (bf16)x, b1 = (bf16)y;
    return ((unsigned int)*(unsigned short*)&b0) | (((unsigned int)*(unsigned short*)&b1) << 16);
}

// LDS-only barrier (no vmcnt drain): safe in loops with no global stores.
__device__ __forceinline__ void barrier_lds() {
    asm volatile("s_waitcnt lgkmcnt(0)" ::: "memory");
    __builtin_amdgcn_s_barrier();
}

// ---------- weight transpose/convert ----------
__global__ void wconv_gen(const float* __restrict__ W, bf16* __restrict__ Wt, int K, int total) {
    int idx = blockIdx.x * 256 + threadIdx.x;
    if (idx >= total) return;
    int per = K * HID;
    int l = idx / per, rem = idx - l * per;
    int n = rem / K, k = rem - n * K;
    Wt[idx] = (bf16)W[(size_t)l * per + (size_t)k * HID + n];
}

__global__ void wconv_pair(const float* __restrict__ Wl, const float* __restrict__ Wr,
                           bf16* __restrict__ Wt) {
    int idx = blockIdx.x * 256 + threadIdx.x;
    int n = idx >> 8, k = idx & 255;
    float v = (n < 256) ? Wl[(size_t)k * HID + n] : Wr[(size_t)k * HID + (n - 256)];
    Wt[idx] = (bf16)v;
}

// ---------- MFMA GEMM (bf16), 128x128 tile, 4-deep register pipeline ----------
// mode 0: +bias (bias2 for cols >= HID)
// mode 2: +bias,relu,bn,leaky AND atomicAdd block stats (sum,sumsq) into stat[0..1]
// mode 3: residual+LN: out = lrelu( (h-mu)*rs*g + b + (acc+bias) ), h reloaded from A
__global__ __launch_bounds__(256) void gemm128(
    const bf16* __restrict__ A, const bf16* __restrict__ Bt,
    const float* __restrict__ bias, const float* __restrict__ bias2,
    bf16* __restrict__ C, int K, int ldc, int mode,
    const float* __restrict__ g, const float* __restrict__ be,
    float* __restrict__ stat)
{
    __shared__ __align__(16) bf16 As[2][128 * SPAD];
    __shared__ __align__(16) bf16 Bs[2][128 * SPAD];
    const int tid = threadIdx.x;
    const int bm = blockIdx.y * 128, bn = blockIdx.x * 128;
    const int w = tid >> 6, lane = tid & 63;
    const int wm = (w & 1) * 64, wn = (w >> 1) * 64;
    const int lrow = lane & 15, lk8 = (lane >> 4) * 8;

    floatx4 acc[4][4];
#pragma unroll
    for (int i = 0; i < 4; i++)
#pragma unroll
        for (int j = 0; j < 4; j++) acc[i][j] = (floatx4){0.f, 0.f, 0.f, 0.f};

    const int r2 = tid >> 1, c2 = tid & 1;
    const bf16* gA = A + (size_t)(bm + r2) * K + c2 * 16;
    const bf16* gB = Bt + (size_t)(bn + r2) * K + c2 * 16;
    bf16* sA = &As[0][r2 * SPAD + c2 * 16];
    bf16* sB = &Bs[0][r2 * SPAD + c2 * 16];

    const int nk = K >> 5;   // 8
    bf16x8 a[4][2], b[4][2];
#pragma unroll
    for (int u = 0; u < 4; u++) {
        const bf16* pa = gA + u * 32;
        a[u][0] = *(const bf16x8*)(pa + 0);
        a[u][1] = *(const bf16x8*)(pa + 8);
        const bf16* pb = gB + u * 32;
        b[u][0] = *(const bf16x8*)(pb + 0);
        b[u][1] = *(const bf16x8*)(pb + 8);
    }

    for (int it0 = 0; it0 < nk; it0 += 4) {
#pragma unroll
        for (int u = 0; u < 4; u++) {
            const int it = it0 + u;
            const int p = u & 1;
            const int po = p * 128 * SPAD;
            *(bf16x8*)(sA + po + 0) = a[u][0];
            *(bf16x8*)(sA + po + 8) = a[u][1];
            *(bf16x8*)(sB + po + 0) = b[u][0];
            *(bf16x8*)(sB + po + 8) = b[u][1];
            barrier_lds();
            if (it + 4 < nk) {
                const bf16* pa = gA + (it + 4) * 32;
                a[u][0] = *(const bf16x8*)(pa + 0);
                a[u][1] = *(const bf16x8*)(pa + 8);
                const bf16* pb = gB + (it + 4) * 32;
                b[u][0] = *(const bf16x8*)(pb + 0);
                b[u][1] = *(const bf16x8*)(pb + 8);
            }
            bf16x8 af[4], bfr[4];
#pragma unroll
            for (int i = 0; i < 4; i++) af[i] = *(const bf16x8*)&As[p][(wm + 16 * i + lrow) * SPAD + lk8];
#pragma unroll
            for (int j = 0; j < 4; j++) bfr[j] = *(const bf16x8*)&Bs[p][(wn + 16 * j + lrow) * SPAD + lk8];
#pragma unroll
            for (int i = 0; i < 4; i++)
#pragma unroll
                for (int j = 0; j < 4; j++)
                    acc[i][j] = __builtin_amdgcn_mfma_f32_16x16x32_bf16(af[i], bfr[j], acc[i][j], 0, 0, 0);
            barrier_lds();
        }
    }

    const float inv = rsqrtf(1.f + EPSC);
    float mu = 0.f, rs = 0.f;
    if (mode == 3) {
        const float inv_n = 1.f / (float)((size_t)N_NODES * HID);
        mu = stat[0] * inv_n;
        float var = stat[1] * inv_n - mu * mu;
        rs = 1.f / (sqrtf(fmaxf(var, 0.f)) + EPSC);
    }
    float sz = 0.f, sq = 0.f;
#pragma unroll
    for (int j = 0; j < 4; j++) {
        int col = bn + wn + 16 * j + lrow;
        float bcol = (col < HID) ? bias[col] : bias2[col - HID];
        float gc = (mode >= 2) ? g[col] : 0.f;
        float bec = (mode >= 2) ? be[col] : 0.f;
#pragma unroll
        for (int i = 0; i < 4; i++) {
            int row0 = bm + wm + 16 * i + (lane >> 4) * 4;
#pragma unroll
            for (int r = 0; r < 4; r++) {
                float z = acc[i][j][r] + bcol;
                if (mode == 2) {
                    z = fmaxf(z, 0.f) * (gc * inv) + bec;
                    z = lrelu(z);
                    sz += z; sq += z * z;
                } else if (mode == 3) {
                    float h = (float)A[(size_t)(row0 + r) * K + col];
                    z = (h - mu) * rs * gc + bec + z;
                    z = lrelu(z);
                }
                C[(size_t)(row0 + r) * ldc + col] = (bf16)z;
            }
        }
    }
    if (mode == 2) {
        for (int o = 32; o > 0; o >>= 1) { sz += __shfl_down(sz, o); sq += __shfl_down(sq, o); }
        __syncthreads();                     // mainloop LDS readers done
        float* rs_ = (float*)&As[0][0];
        float* rq_ = (float*)&Bs[0][0];
        if (lane == 0) { rs_[w] = sz; rq_[w] = sq; }
        __syncthreads();
        if (tid == 0) {
            atomicAdd(&stat[0], rs_[0] + rs_[1] + rs_[2] + rs_[3]);
            atomicAdd(&stat[1], rq_[0] + rq_[1] + rq_[2] + rq_[3]);
        }
    }
}

// ---------- MFMA GEMM (fp32 A), 128x128 tile, depth-4 pipeline (champion, CLOSED) ----------
__global__ __launch_bounds__(256, 1) void gemm_f32A(
    const float* __restrict__ A, const bf16* __restrict__ Bt,
    const float* __restrict__ bias, bf16* __restrict__ C, int K,
    const float* __restrict__ g, const float* __restrict__ be)
{
    __shared__ __align__(16) bf16 As[2][128 * SPAD];
    __shared__ __align__(16) bf16 Bs[2][128 * SPAD];
    const int tid = threadIdx.x;
    const int bm = blockIdx.y * 128, bn = blockIdx.x * 128;
    const int w = tid >> 6, lane = tid & 63;
    const int wm = (w & 1) * 64, wn = (w >> 1) * 64;
    const int lrow = lane & 15, lk8 = (lane >> 4) * 8;

    floatx4 acc[4][4];
#pragma unroll
    for (int i = 0; i < 4; i++)
#pragma unroll
        for (int j = 0; j < 4; j++) acc[i][j] = (floatx4){0.f, 0.f, 0.f, 0.f};

    const int r2 = tid >> 1, c2 = tid & 1;
    const float* gA = A + (size_t)(bm + r2) * K + c2 * 16;
    const bf16* gB = Bt + (size_t)(bn + r2) * K + c2 * 16;
    bf16* sA = &As[0][r2 * SPAD + c2 * 16];
    bf16* sB = &Bs[0][r2 * SPAD + c2 * 16];

    const int nk = K >> 5;   // 40
    float4 a[4][4];
    bf16x8 b[4][2];
#pragma unroll
    for (int u = 0; u < 4; u++) {
        const float* pa = gA + u * 32;
        a[u][0] = *(const float4*)(pa + 0);
        a[u][1] = *(const float4*)(pa + 4);
        a[u][2] = *(const float4*)(pa + 8);
        a[u][3] = *(const float4*)(pa + 12);
        const bf16* pb = gB + u * 32;
        b[u][0] = *(const bf16x8*)(pb + 0);
        b[u][1] = *(const bf16x8*)(pb + 8);
    }

    for (int it0 = 0; it0 < nk; it0 += 4) {
#pragma unroll
        for (int u = 0; u < 4; u++) {
            const int it = it0 + u;
            const int p = u & 1;
            const int po = p * 128 * SPAD;
            bf16x8 h0, h1;
            h0[0] = (bf16)a[u][0].x; h0[1] = (bf16)a[u][0].y; h0[2] = (bf16)a[u][0].z; h0[3] = (bf16)a[u][0].w;
            h0[4] = (bf16)a[u][1].x; h0[5] = (bf16)a[u][1].y; h0[6] = (bf16)a[u][1].z; h0[7] = (bf16)a[u][1].w;
            h1[0] = (bf16)a[u][2].x; h1[1] = (bf16)a[u][2].y; h1[2] = (bf16)a[u][2].z; h1[3] = (bf16)a[u][2].w;
            h1[4] = (bf16)a[u][3].x; h1[5] = (bf16)a[u][3].y; h1[6] = (bf16)a[u][3].z; h1[7] = (bf16)a[u][3].w;
            *(bf16x8*)(sA + po + 0) = h0;
            *(bf16x8*)(sA + po + 8) = h1;
            *(bf16x8*)(sB + po + 0) = b[u][0];
            *(bf16x8*)(sB + po + 8) = b[u][1];
            barrier_lds();
            if (it + 4 < nk) {
                const float* pa = gA + (it + 4) * 32;
                a[u][0] = *(const float4*)(pa + 0);
                a[u][1] = *(const float4*)(pa + 4);
                a[u][2] = *(const float4*)(pa + 8);
                a[u][3] = *(const float4*)(pa + 12);
                const bf16* pb = gB + (it + 4) * 32;
                b[u][0] = *(const bf16x8*)(pb + 0);
                b[u][1] = *(const bf16x8*)(pb + 8);
            }
            bf16x8 af[4], bfr[4];
#pragma unroll
            for (int i = 0; i < 4; i++) af[i] = *(const bf16x8*)&As[p][(wm + 16 * i + lrow) * SPAD + lk8];
#pragma unroll
            for (int j = 0; j < 4; j++) bfr[j] = *(const bf16x8*)&Bs[p][(wn + 16 * j + lrow) * SPAD + lk8];
#pragma unroll
            for (int i = 0; i < 4; i++)
#pragma unroll
                for (int j = 0; j < 4; j++)
                    acc[i][j] = __builtin_amdgcn_mfma_f32_16x16x32_bf16(af[i], bfr[j], acc[i][j], 0, 0, 0);
            barrier_lds();
        }
    }

    const float inv = rsqrtf(1.f + EPSC);
#pragma unroll
    for (int j = 0; j < 4; j++) {
        int col = bn + wn + 16 * j + lrow;
        float bcol = bias[col];
        float gc = g[col] * inv;
        float bec = be[col];
#pragma unroll
        for (int i = 0; i < 4; i++) {
            int row0 = bm + wm + 16 * i + (lane >> 4) * 4;
#pragma unroll
            for (int r = 0; r < 4; r++) {
                float z = fmaxf(acc[i][j][r] + bcol, 0.f) * gc + bec;
                C[(size_t)(row0 + r) * HID + col] = (bf16)z;
            }
        }
    }
}

// ---------- CSR build ----------
__global__ void hist_kernel(const int* __restrict__ ei, int* __restrict__ cnt) {
    int e = blockIdx.x * 256 + threadIdx.x;
    if (e >= EPE) return;
    int d = (e < N_EDGES) ? ei[N_EDGES + e] : (e - N_EDGES);
    atomicAdd(&cnt[d], 1);
}

__global__ __launch_bounds__(1024) void scan_kernel(const int* __restrict__ cnt,
                                                    int* __restrict__ roff, int* __restrict__ cursor,
                                                    const int* __restrict__ batch,
                                                    int* __restrict__ gstart) {
    __shared__ int wsum[16];
    int t = threadIdx.x;
    int base = t * 16;
    int local[16]; int s = 0;
#pragma unroll
    for (int i = 0; i < 16; i++) {
        int idx = base + i;
        int v = (idx < N_NODES) ? cnt[idx] : 0;
        local[i] = s; s += v;
    }
    int lane = t & 63, wid = t >> 6;
    int incl = s;
    for (int o = 1; o < 64; o <<= 1) { int v = __shfl_up(incl, o); if (lane >= o) incl += v; }
    if (lane == 63) wsum[wid] = incl;
    __syncthreads();
    if (t == 0) { int a = 0; for (int k = 0; k < 16; k++) { int v = wsum[k]; wsum[k] = a; a += v; } }
    __syncthreads();
    int texcl = incl - s + wsum[wid];
#pragma unroll
    for (int i = 0; i < 16; i++) {
        int idx = base + i;
        if (idx < N_NODES) { int o = texcl + local[i]; roff[idx] = o; cursor[idx] = o; }
    }
    if (t == 1023) roff[N_NODES] = texcl + s;
    if (t <= NG) {
        int lo = 0, hi = N_NODES;
        while (lo < hi) { int mid = (lo + hi) >> 1; if (batch[mid] < t) lo = mid + 1; else hi = mid; }
        gstart[t] = lo;
    }
}

__global__ void scatter_kernel(const int* __restrict__ ei, int* __restrict__ cursor,
                               int* __restrict__ esrc) {
    int e = blockIdx.x * 256 + threadIdx.x;
    if (e >= EPE) return;
    int s, d;
    if (e < N_EDGES) { s = ei[e]; d = ei[N_EDGES + e]; }
    else { s = d = e - N_EDGES; }
    int pos = atomicAdd(&cursor[d], 1);
    esrc[pos] = s;
}

// ---------- wave-per-dst GATv2: 4 edges/iter ----------
__global__ __launch_bounds__(256) void gat_wave(
    const bf16* __restrict__ XLR, const int* __restrict__ roff, const int* __restrict__ esrc,
    const float* __restrict__ att, const float* __restrict__ gbias, bf16* __restrict__ out)
{
    const int wid = threadIdx.x >> 6;
    const int lane = threadIdx.x & 63;
    const int d = blockIdx.x * 4 + wid;
    const int beg = roff[d], end = roff[d + 1];
    const int c0 = lane * 4;

    const unsigned int* xru = (const unsigned int*)(XLR + (size_t)d * 512 + 256 + c0);
    const unsigned int xr01 = xru[0], xr23 = xru[1];
    const float xr0 = bflo(xr01), xr1 = bfhi(xr01), xr2 = bflo(xr23), xr3 = bfhi(xr23);
    const float at0 = att[c0], at1 = att[c0 + 1], at2 = att[c0 + 2], at3 = att[c0 + 3];

    float m = -INFINITY, s = 0.f;
    float a0 = 0.f, a1 = 0.f, a2 = 0.f, a3 = 0.f;

    int e = beg;
    for (; e + 3 < end; e += 4) {
        int s0 = esrc[e], s1 = esrc[e + 1], s2 = esrc[e + 2], s3 = esrc[e + 3];
        const unsigned int* q0 = (const unsigned int*)(XLR + (size_t)s0 * 512 + c0);
        const unsigned int* q1 = (const unsigned int*)(XLR + (size_t)s1 * 512 + c0);
        const unsigned int* q2 = (const unsigned int*)(XLR + (size_t)s2 * 512 + c0);
        const unsigned int* q3 = (const unsigned int*)(XLR + (size_t)s3 * 512 + c0);
        unsigned int u01 = q0[0], u23 = q0[1];
        unsigned int v01 = q1[0], v23 = q1[1];
        unsigned int w01 = q2[0], w23 = q2[1];
        unsigned int x01 = q3[0], x23 = q3[1];
        float x0 = bflo(u01), x1 = bfhi(u01), x2 = bflo(u23), x3 = bfhi(u23);
        float y0 = bflo(v01), y1 = bfhi(v01), y2 = bflo(v23), y3 = bfhi(v23);
        float z0 = bflo(w01), z1 = bfhi(w01), z2 = bflo(w23), z3 = bfhi(w23);
        float t0 = bflo(x01), t1 = bfhi(x01), t2 = bflo(x23), t3 = bfhi(x23);
        float p0 = lrelu(x0 + xr0) * at0 + lrelu(x1 + xr1) * at1
                 + lrelu(x2 + xr2) * at2 + lrelu(x3 + xr3) * at3;
        float p1 = lrelu(y0 + xr0) * at0 + lrelu(y1 + xr1) * at1
                 + lrelu(y2 + xr2) * at2 + lrelu(y3 + xr3) * at3;
        float p2 = lrelu(z0 + xr0) * at0 + lrelu(z1 + xr1) * at1
                 + lrelu(z2 + xr2) * at2 + lrelu(z3 + xr3) * at3;
        float p3 = lrelu(t0 + xr0) * at0 + lrelu(t1 + xr1) * at1
                 + lrelu(t2 + xr2) * at2 + lrelu(t3 + xr3) * at3;
        p0 += __shfl_xor(p0, 1);  p1 += __shfl_xor(p1, 1);
        p2 += __shfl_xor(p2, 1);  p3 += __shfl_xor(p3, 1);
        p0 += __shfl_xor(p0, 2);  p1 += __shfl_xor(p1, 2);
        p2 += __shfl_xor(p2, 2);  p3 += __shfl_xor(p3, 2);
        p0 += __shfl_xor(p0, 4);  p1 += __shfl_xor(p1, 4);
        p2 += __shfl_xor(p2, 4);  p3 += __shfl_xor(p3, 4);
        float mn = fmaxf(fmaxf(m, fmaxf(p0, p1)), fmaxf(p2, p3));
        float rsc = __expf(m - mn);              // first iter: exp(-inf)=0
        float w0 = __expf(p0 - mn);
        float w1 = __expf(p1 - mn);
        float w2 = __expf(p2 - mn);
        float w3 = __expf(p3 - mn);
        s = s * rsc + (w0 + w1) + (w2 + w3);
        a0 = a0 * rsc + (w0 * x0 + w1 * y0) + (w2 * z0 + w3 * t0);
        a1 = a1 * rsc + (w0 * x1 + w1 * y1) + (w2 * z1 + w3 * t1);
        a2 = a2 * rsc + (w0 * x2 + w1 * y2) + (w2 * z2 + w3 * t2);
        a3 = a3 * rsc + (w0 * x3 + w1 * y3) + (w2 * z3 + w3 * t3);
        m = mn;
    }
    for (; e < end; ++e) {                       // tail (0-3 edges)
        int s0 = esrc[e];
        const unsigned int* q0 = (const unsigned int*)(XLR + (size_t)s0 * 512 + c0);
        unsigned int u01 = q0[0], u23 = q0[1];
        float x0 = bflo(u01), x1 = bfhi(u01), x2 = bflo(u23), x3 = bfhi(u23);
        float p = lrelu(x0 + xr0) * at0 + lrelu(x1 + xr1) * at1
                + lrelu(x2 + xr2) * at2 + lrelu(x3 + xr3) * at3;
        p += __shfl_xor(p, 1);
        p += __shfl_xor(p, 2);
        p += __shfl_xor(p, 4);
        float mn = fmaxf(m, p);
        float rsc = __expf(m - mn);
        float wgt = __expf(p - mn);
        s = s * rsc + wgt;
        a0 = a0 * rsc + wgt * x0;
        a1 = a1 * rsc + wgt * x1;
        a2 = a2 * rsc + wgt * x2;
        a3 = a3 * rsc + wgt * x3;
        m = mn;
    }

    const float rinv = 1.f / (s + 1e-16f);
    float v0 = gbias[c0]     + a0 * rinv;
    float v1 = gbias[c0 + 1] + a1 * rinv;
    float v2 = gbias[c0 + 2] + a2 * rinv;
    float v3 = gbias[c0 + 3] + a3 * rinv;
    unsigned int* op = (unsigned int*)(out + (size_t)d * HID + c0);
    op[0] = bfpack(v0, v1);
    op[1] = bfpack(v2, v3);
}

// ---------- wave-per-dst GIN gather (4 gathers in flight) + zero stat ----------
__global__ __launch_bounds__(256) void gin_wave(
    const bf16* __restrict__ H, const int* __restrict__ roff,
    const int* __restrict__ esrc, bf16* __restrict__ U, float* __restrict__ stat)
{
    if (blockIdx.x == 0 && threadIdx.x == 0) { stat[0] = 0.f; stat[1] = 0.f; }
    const int wid = threadIdx.x >> 6;
    const int lane = threadIdx.x & 63;
    const int d = blockIdx.x * 4 + wid;
    const int beg = roff[d], end = roff[d + 1];
    const int c0 = lane * 4;

    float a0 = 0.f, a1 = 0.f, a2 = 0.f, a3 = 0.f;
    int e = beg;
    for (; e + 3 < end; e += 4) {
        int s0 = esrc[e], s1 = esrc[e + 1], s2 = esrc[e + 2], s3 = esrc[e + 3];
        const unsigned int* p0 = (const unsigned int*)(H + (size_t)s0 * HID + c0);
        const unsigned int* p1 = (const unsigned int*)(H + (size_t)s1 * HID + c0);
        const unsigned int* p2 = (const unsigned int*)(H + (size_t)s2 * HID + c0);
        const unsigned int* p3 = (const unsigned int*)(H + (size_t)s3 * HID + c0);
        unsigned int u01 = p0[0], u23 = p0[1];
        unsigned int v01 = p1[0], v23 = p1[1];
        unsigned int w01 = p2[0], w23 = p2[1];
        unsigned int x01 = p3[0], x23 = p3[1];
        a0 += (bflo(u01) + bflo(v01)) + (bflo(w01) + bflo(x01));
        a1 += (bfhi(u01) + bfhi(v01)) + (bfhi(w01) + bfhi(x01));
        a2 += (bflo(u23) + bflo(v23)) + (bflo(w23) + bflo(x23));
        a3 += (bfhi(u23) + bfhi(v23)) + (bfhi(w23) + bfhi(x23));
    }
    for (; e < end; ++e) {
        const unsigned int* p0 = (const unsigned int*)(H + (size_t)esrc[e] * HID + c0);
        unsigned int u01 = p0[0], u23 = p0[1];
        a0 += bflo(u01); a1 += bfhi(u01); a2 += bflo(u23); a3 += bfhi(u23);
    }
    unsigned int* up = (unsigned int*)(U + (size_t)d * HID + c0);
    up[0] = bfpack(a0, a1);
    up[1] = bfpack(a2, a3);
}

// ---------- pooling ----------
__global__ __launch_bounds__(256) void pool_gate_kernel(const bf16* __restrict__ t,
    const float* __restrict__ W2, const float* __restrict__ b2, float* __restrict__ gate)
{
    int n = blockIdx.x * 4 + (threadIdx.x >> 6);
    int lane = threadIdx.x & 63;
    const bf16* p = t + (size_t)n * HID + lane * 4;
    float4 w = *(const float4*)(W2 + lane * 4);
    float s = tanhf((float)p[0]) * w.x + tanhf((float)p[1]) * w.y
            + tanhf((float)p[2]) * w.z + tanhf((float)p[3]) * w.w;
    for (int o = 32; o > 0; o >>= 1) s += __shfl_down(s, o);
    if (lane == 0) gate[n] = s + b2[0];
}

__global__ __launch_bounds__(256) void pool_stats_kernel(
    float* __restrict__ gate, const int* __restrict__ gstart)
{
    int g = blockIdx.x, t = threadIdx.x;
    int lo = gstart[g], hi = gstart[g + 1];
    __shared__ float red[256];
    float m = -INFINITY;
    for (int n = lo + t; n < hi; n += 256) m = fmaxf(m, gate[n]);
    red[t] = m; __syncthreads();
    for (int st = 128; st > 0; st >>= 1) { if (t < st) red[t] = fmaxf(red[t], red[t + st]); __syncthreads(); }
    m = red[0]; __syncthreads();
    float s = 0.f;
    for (int n = lo + t; n < hi; n += 256) s += __expf(gate[n] - m);
    red[t] = s; __syncthreads();
    for (int st = 128; st > 0; st >>= 1) { if (t < st) red[t] += red[t + st]; __syncthreads(); }
    float sinv = 1.f / (red[0] + 1e-16f);
    for (int n = lo + t; n < hi; n += 256) gate[n] = __expf(gate[n] - m) * sinv;
}

__global__ __launch_bounds__(256) void emb_accum_kernel(
    const float* __restrict__ a, const int* __restrict__ batch,
    const bf16* __restrict__ h, float* __restrict__ emb)
{
    int n0 = blockIdx.x * 32, t = threadIdx.x;
    int cur = batch[n0]; float acc = 0.f;
    for (int j = 0; j < 32; j++) {
        int n = n0 + j;
        int b = batch[n];
        if (b != cur) { atomicAdd(&emb[cur * HID + t], acc); cur = b; acc = 0.f; }
        acc += a[n] * (float)h[(size_t)n * HID + t];
    }
    atomicAdd(&emb[cur * HID + t], acc);
}

// ---------- label heads: block = (label, channel-quarter). W1 read once ----------
// 256 blocks (1/CU). Thread owns channel c = q*64+(t&63) and 8 graphs (t>>6).
// emb staged in LDS (broadcast reads); acc[8] in registers. Epilogue:
// silu/bn/W2-scale, 64-lane shuffle-sum over channels, atomicAdd partial into
// pre-zeroed out (b2 added by q==0 block only). All fp32.
__global__ __launch_bounds__(256) void heads_kernel(
    const float* __restrict__ emb, const float* __restrict__ W1, const float* __restrict__ b1,
    const float* __restrict__ hg, const float* __restrict__ hbe, const float* __restrict__ W2,
    const float* __restrict__ b2, float* __restrict__ out)
{
    const int o = blockIdx.x;
    const int q = blockIdx.y;
    const int t = threadIdx.x;
    const int c = q * 64 + (t & 63);
    const int gg = t >> 6;              // graph group of 8
    __shared__ float se[NG][HID];       // 32 KB
#pragma unroll
    for (int i = 0; i < 8; i++)
        ((float4*)&se[0][0])[t + i * 256] = ((const float4*)emb)[t + i * 256];
    __syncthreads();

    const float* w1p = W1 + (size_t)o * HID * HID + c;
    const float zb = b1[o * HID + c];
    float acc[8];
#pragma unroll
    for (int j = 0; j < 8; j++) acc[j] = zb;

    for (int d4 = 0; d4 < HID; d4 += 4) {
        float w0  = w1p[(size_t)(d4 + 0) * HID];
        float w1v = w1p[(size_t)(d4 + 1) * HID];
        float w2v = w1p[(size_t)(d4 + 2) * HID];
        float w3v = w1p[(size_t)(d4 + 3) * HID];
#pragma unroll
        for (int j = 0; j < 8; j++) {
            float4 s4 = *(const float4*)&se[gg * 8 + j][d4];
            acc[j] = fmaf(s4.x, w0,  acc[j]);
            acc[j] = fmaf(s4.y, w1v, acc[j]);
            acc[j] = fmaf(s4.z, w2v, acc[j]);
            acc[j] = fmaf(s4.w, w3v, acc[j]);
        }
    }

    const float gk = hg[o * HID + c] * rsqrtf(1.f + EPSC);
    const float bek = hbe[o * HID + c];
    const float w2c = W2[o * HID + c];
    const float b2o = b2[o];
    const int lane = t & 63;
#pragma unroll
    for (int j = 0; j < 8; j++) {
        float z = acc[j];
        float sil = z / (1.f + expf(-z));
        float v = (sil * gk + bek) * w2c;
        for (int off = 32; off > 0; off >>= 1) v += __shfl_down(v, off);
        if (lane == 0) {
            if (q == 0) v += b2o;
            atomicAdd(&out[(gg * 8 + j) * NO + o], v);
        }
    }
}

extern "C" void kernel_launch(void* const* d_in, const int* in_sizes, int n_in,
                              void* d_out, int out_size, void* d_ws, size_t ws_size,
                              hipStream_t stream) {
    const float* x        = (const float*)d_in[0];
    const int*   ei       = (const int*)  d_in[1];
    const int*   batch    = (const int*)  d_in[2];
    const float* fp_W     = (const float*)d_in[3];
    const float* fp_b     = (const float*)d_in[4];
    const float* fp_g     = (const float*)d_in[5];
    const float* fp_be    = (const float*)d_in[6];
    const float* gat_Wl   = (const float*)d_in[7];
    const float* gat_bl   = (const float*)d_in[8];
    const float* gat_Wr   = (const float*)d_in[9];
    const float* gat_br   = (const float*)d_in[10];
    const float* gat_att  = (const float*)d_in[11];
    const float* gat_bias = (const float*)d_in[12];
    const float* gin_W    = (const float*)d_in[13];
    const float* gin_b    = (const float*)d_in[14];
    const float* gin_g    = (const float*)d_in[15];
    const float* gin_be   = (const float*)d_in[16];
    const float* ln_g     = (const float*)d_in[17];
    const float* ln_b     = (const float*)d_in[18];
    const float* res_W    = (const float*)d_in[19];
    const float* res_b    = (const float*)d_in[20];
    const float* pool_W1  = (const float*)d_in[21];
    const float* pool_b1  = (const float*)d_in[22];
    const float* pool_W2  = (const float*)d_in[23];
    const float* pool_b2  = (const float*)d_in[24];
    const float* head_W1  = (const float*)d_in[25];
    const float* head_b1  = (const float*)d_in[26];
    const float* head_g   = (const float*)d_in[27];
    const float* head_be  = (const float*)d_in[28];
    const float* head_W2  = (const float*)d_in[29];
    const float* head_b2  = (const float*)d_in[30];
    float* out = (float*)d_out;

    char* base = (char*)d_ws;
    size_t off = 0;
    auto alloc = [&](size_t bytes) -> char* {
        char* p = base + off; off += (bytes + 255) & ~(size_t)255; return p;
    };
    int*   esrc   = (int*)  alloc((size_t)EPE * 4);
    int*   cnt    = (int*)  alloc((size_t)N_NODES * 4);
    int*   roff   = (int*)  alloc((size_t)(N_NODES + 1) * 4);
    int*   cursor = (int*)  alloc((size_t)N_NODES * 4);
    float* gate   = (float*)alloc((size_t)N_NODES * 4);
    int*   gstart = (int*)  alloc((NG + 1) * 4);
    float* emb    = (float*)alloc(NG * HID * 4);
    float* stat   = (float*)alloc(8);
    bf16*  Hb0    = (bf16*) alloc((size_t)N_NODES * HID * 2);
    bf16*  Hb1    = (bf16*) alloc((size_t)N_NODES * HID * 2);
    bf16*  XLR    = (bf16*) alloc((size_t)N_NODES * 512 * 2);
    bf16*  fpWt   = (bf16*) alloc((size_t)DIN * HID * 2);
    bf16*  wlrT0  = (bf16*) alloc((size_t)512 * HID * 2);
    bf16*  wlrT1  = (bf16*) alloc((size_t)512 * HID * 2);
    bf16*  gwT    = (bf16*) alloc((size_t)2 * HID * HID * 2);
    bf16*  rwT    = (bf16*) alloc((size_t)2 * HID * HID * 2);
    bf16*  pwT    = (bf16*) alloc((size_t)HID * HID * 2);
    bf16*  Ub     = XLR;
    bf16*  wlrT[2] = { wlrT0, wlrT1 };

    // ---- weight conversions (small concurrent kernels) ----
    wconv_gen<<<(DIN * HID + 255) / 256, 256, 0, stream>>>(fp_W, fpWt, DIN, DIN * HID);
    wconv_pair<<<512, 256, 0, stream>>>(gat_Wl, gat_Wr, wlrT0);
    wconv_pair<<<512, 256, 0, stream>>>(gat_Wl + HID * HID, gat_Wr + HID * HID, wlrT1);
    wconv_gen<<<512, 256, 0, stream>>>(gin_W, gwT, HID, 2 * HID * HID);
    wconv_gen<<<512, 256, 0, stream>>>(res_W, rwT, HID, 2 * HID * HID);
    wconv_gen<<<256, 256, 0, stream>>>(pool_W1, pwT, HID, HID * HID);

    // ---- CSR build (+ graph boundaries fused into scan) ----
    hipMemsetAsync(cnt, 0, N_NODES * sizeof(int), stream);
    hist_kernel<<<(EPE + 255) / 256, 256, 0, stream>>>(ei, cnt);
    scan_kernel<<<1, 1024, 0, stream>>>(cnt, roff, cursor, batch, gstart);
    scatter_kernel<<<(EPE + 255) / 256, 256, 0, stream>>>(ei, cursor, esrc);

    // ---- feature projection (128x128 tiles, depth-4, champion config) ----
    dim3 gridF(2, 125);
    dim3 g128_256(2, 125);       // 128x128 tiles, 256 cols
    dim3 g128_512(4, 125);       // 128x128 tiles, 512 cols
    gemm_f32A<<<gridF, 256, 0, stream>>>(x, fpWt, fp_b, Hb0, DIN, fp_g, fp_be);

    bf16* hcur = Hb0;
    bf16* hoth = Hb1;
    for (int i = 0; i < 2; i++) {
        // xl|xr
        gemm128<<<g128_512, 256, 0, stream>>>(hcur, wlrT[i], gat_bl + i * HID, gat_br + i * HID,
                                              XLR, HID, 512, 0, nullptr, nullptr, nullptr);
        // GAT -> hoth (wave-per-dst, 4 edges/iter)
        gat_wave<<<N_NODES / 4, 256, 0, stream>>>(XLR, roff, esrc, gat_att + i * HEADS * CPH,
                                                  gat_bias + i * HID, hoth);
        // GIN aggregate -> Ub (wave-per-dst, 4 gathers/iter), zeroes stat
        gin_wave<<<N_NODES / 4, 256, 0, stream>>>(hoth, roff, esrc, Ub, stat);
        // h_gin = leaky(BN(relu(u@W+b))) -> hcur, stats atomically into stat
        gemm128<<<g128_256, 256, 0, stream>>>(Ub, gwT + (size_t)i * HID * HID, gin_b + i * HID,
                                              nullptr, hcur, HID, HID, 2,
                                              gin_g + i * HID, gin_be + i * HID, stat);
        // h = leaky(LN(h_gin) + h_gin@res_W + res_b) -> hoth
        gemm128<<<g128_256, 256, 0, stream>>>(hcur, rwT + (size_t)i * HID * HID, res_b + i * HID,
                                              nullptr, hoth, HID, HID, 3,
                                              ln_g + i * HID, ln_b + i * HID, stat);
        bf16* tmp = hcur; hcur = hoth; hoth = tmp;
    }

    // ---- global attention pooling ----
    gemm128<<<g128_256, 256, 0, stream>>>(hcur, pwT, pool_b1, nullptr, hoth, HID, HID, 0,
                                          nullptr, nullptr, nullptr);
    pool_gate_kernel<<<N_NODES / 4, 256, 0, stream>>>(hoth, pool_W2, pool_b2, gate);
    pool_stats_kernel<<<NG, 256, 0, stream>>>(gate, gstart);
    hipMemsetAsync(emb, 0, NG * HID * sizeof(float), stream);
    emb_accum_kernel<<<N_NODES / 32, 256, 0, stream>>>(gate, batch, hcur, emb);

    // ---- label heads (256 blocks: label x channel-quarter; out pre-zeroed) ----
    hipMemsetAsync(out, 0, NG * NO * sizeof(float), stream);
    dim3 hgrid(NO, 4);
    heads_kernel<<<hgrid, 256, 0, stream>>>(emb, head_W1, head_b1, head_g, head_be,
                                            head_W2, head_b2, out);
}

// Round 13
// 523.863 us; speedup vs baseline: 1.1383x; 1.0268x over previous
//
#include <hip/hip_runtime.h>
#include <math.h>

#define N_NODES 16000
#define N_EDGES 256000
#define EPE (N_EDGES + N_NODES)
#define DIN 1280
#define HID 256
#define HEADS 8
#define CPH 32
#define NG 32
#define NO 64
#define EPSC 1e-5f
#define SPAD 40     // GEMM LDS row stride (bf16): 80 B, 16B-aligned

typedef __bf16 bf16;
typedef __attribute__((ext_vector_type(8))) __bf16 bf16x8;
typedef __attribute__((ext_vector_type(4))) float floatx4;

__device__ __forceinline__ float lrelu(float v) { return v > 0.f ? v : 0.2f * v; }
__device__ __forceinline__ float bflo(unsigned int u) { return __uint_as_float(u << 16); }
__device__ __forceinline__ float bfhi(unsigned int u) { return __uint_as_float(u & 0xffff0000u); }
__device__ __forceinline__ unsigned int bfpack(float x, float y) {
    bf16 b0 = (bf16)x, b1 = (bf16)y;
    return ((unsigned int)*(unsigned short*)&b0) | (((unsigned int)*(unsigned short*)&b1) << 16);
}

// LDS-only barrier (no vmcnt drain): safe in loops with no global stores.
__device__ __forceinline__ void barrier_lds() {
    asm volatile("s_waitcnt lgkmcnt(0)" ::: "memory");
    __builtin_amdgcn_s_barrier();
}

// ---------- fused weight transpose/convert (1 launch; segments multiple of 256) ----------
__global__ __launch_bounds__(256) void wconv_all(
    const float* __restrict__ fp_W, const float* __restrict__ gat_Wl,
    const float* __restrict__ gat_Wr, const float* __restrict__ gin_W,
    const float* __restrict__ res_W, const float* __restrict__ pool_W1,
    bf16* __restrict__ fpWt, bf16* __restrict__ wlrT0, bf16* __restrict__ wlrT1,
    bf16* __restrict__ gwT, bf16* __restrict__ rwT, bf16* __restrict__ pwT)
{
    int idx = blockIdx.x * 256 + threadIdx.x;
    if (idx < 327680) {                       // fpWt [256][1280] <- fp_W [1280][256]
        int n = idx / 1280, k = idx - n * 1280;
        fpWt[idx] = (bf16)fp_W[k * 256 + n];
    } else if (idx < 458752) {                // wlrT0 [512][256]
        int r = idx - 327680; int n = r >> 8, k = r & 255;
        wlrT0[r] = (bf16)(n < 256 ? gat_Wl[k * 256 + n] : gat_Wr[k * 256 + (n - 256)]);
    } else if (idx < 589824) {                // wlrT1 [512][256]
        int r = idx - 458752; int n = r >> 8, k = r & 255;
        wlrT1[r] = (bf16)(n < 256 ? gat_Wl[65536 + k * 256 + n]
                                  : gat_Wr[65536 + k * 256 + (n - 256)]);
    } else if (idx < 720896) {                // gwT 2x[256][256]
        int r = idx - 589824; int l = r >> 16, rr = r & 65535;
        int n = rr >> 8, k = rr & 255;
        gwT[r] = (bf16)gin_W[l * 65536 + k * 256 + n];
    } else if (idx < 851968) {                // rwT 2x[256][256]
        int r = idx - 720896; int l = r >> 16, rr = r & 65535;
        int n = rr >> 8, k = rr & 255;
        rwT[r] = (bf16)res_W[l * 65536 + k * 256 + n];
    } else {                                  // pwT [256][256]
        int r = idx - 851968; int n = r >> 8, k = r & 255;
        pwT[r] = (bf16)pool_W1[k * 256 + n];
    }
}

// ---------- MFMA GEMM (bf16), 128x128 tile, 4-deep register pipeline ----------
// mode 0: +bias (bias2 for cols >= HID)
// mode 2: +bias,relu,bn,leaky AND atomicAdd block stats (sum,sumsq) into stat[0..1]
// mode 3: residual+LN: out = lrelu( (h-mu)*rs*g + b + (acc+bias) ), h reloaded from A
__global__ __launch_bounds__(256) void gemm128(
    const bf16* __restrict__ A, const bf16* __restrict__ Bt,
    const float* __restrict__ bias, const float* __restrict__ bias2,
    bf16* __restrict__ C, int K, int ldc, int mode,
    const float* __restrict__ g, const float* __restrict__ be,
    float* __restrict__ stat)
{
    __shared__ __align__(16) bf16 As[2][128 * SPAD];
    __shared__ __align__(16) bf16 Bs[2][128 * SPAD];
    const int tid = threadIdx.x;
    const int bm = blockIdx.y * 128, bn = blockIdx.x * 128;
    const int w = tid >> 6, lane = tid & 63;
    const int wm = (w & 1) * 64, wn = (w >> 1) * 64;
    const int lrow = lane & 15, lk8 = (lane >> 4) * 8;

    floatx4 acc[4][4];
#pragma unroll
    for (int i = 0; i < 4; i++)
#pragma unroll
        for (int j = 0; j < 4; j++) acc[i][j] = (floatx4){0.f, 0.f, 0.f, 0.f};

    const int r2 = tid >> 1, c2 = tid & 1;
    const bf16* gA = A + (size_t)(bm + r2) * K + c2 * 16;
    const bf16* gB = Bt + (size_t)(bn + r2) * K + c2 * 16;
    bf16* sA = &As[0][r2 * SPAD + c2 * 16];
    bf16* sB = &Bs[0][r2 * SPAD + c2 * 16];

    const int nk = K >> 5;   // 8
    bf16x8 a[4][2], b[4][2];
#pragma unroll
    for (int u = 0; u < 4; u++) {
        const bf16* pa = gA + u * 32;
        a[u][0] = *(const bf16x8*)(pa + 0);
        a[u][1] = *(const bf16x8*)(pa + 8);
        const bf16* pb = gB + u * 32;
        b[u][0] = *(const bf16x8*)(pb + 0);
        b[u][1] = *(const bf16x8*)(pb + 8);
    }

    for (int it0 = 0; it0 < nk; it0 += 4) {
#pragma unroll
        for (int u = 0; u < 4; u++) {
            const int it = it0 + u;
            const int p = u & 1;
            const int po = p * 128 * SPAD;
            *(bf16x8*)(sA + po + 0) = a[u][0];
            *(bf16x8*)(sA + po + 8) = a[u][1];
            *(bf16x8*)(sB + po + 0) = b[u][0];
            *(bf16x8*)(sB + po + 8) = b[u][1];
            barrier_lds();
            if (it + 4 < nk) {
                const bf16* pa = gA + (it + 4) * 32;
                a[u][0] = *(const bf16x8*)(pa + 0);
                a[u][1] = *(const bf16x8*)(pa + 8);
                const bf16* pb = gB + (it + 4) * 32;
                b[u][0] = *(const bf16x8*)(pb + 0);
                b[u][1] = *(const bf16x8*)(pb + 8);
            }
            bf16x8 af[4], bfr[4];
#pragma unroll
            for (int i = 0; i < 4; i++) af[i] = *(const bf16x8*)&As[p][(wm + 16 * i + lrow) * SPAD + lk8];
#pragma unroll
            for (int j = 0; j < 4; j++) bfr[j] = *(const bf16x8*)&Bs[p][(wn + 16 * j + lrow) * SPAD + lk8];
#pragma unroll
            for (int i = 0; i < 4; i++)
#pragma unroll
                for (int j = 0; j < 4; j++)
                    acc[i][j] = __builtin_amdgcn_mfma_f32_16x16x32_bf16(af[i], bfr[j], acc[i][j], 0, 0, 0);
            barrier_lds();
        }
    }

    const float inv = rsqrtf(1.f + EPSC);
    float mu = 0.f, rs = 0.f;
    if (mode == 3) {
        const float inv_n = 1.f / (float)((size_t)N_NODES * HID);
        mu = stat[0] * inv_n;
        float var = stat[1] * inv_n - mu * mu;
        rs = 1.f / (sqrtf(fmaxf(var, 0.f)) + EPSC);
    }
    float sz = 0.f, sq = 0.f;
#pragma unroll
    for (int j = 0; j < 4; j++) {
        int col = bn + wn + 16 * j + lrow;
        float bcol = (col < HID) ? bias[col] : bias2[col - HID];
        float gc = (mode >= 2) ? g[col] : 0.f;
        float bec = (mode >= 2) ? be[col] : 0.f;
#pragma unroll
        for (int i = 0; i < 4; i++) {
            int row0 = bm + wm + 16 * i + (lane >> 4) * 4;
#pragma unroll
            for (int r = 0; r < 4; r++) {
                float z = acc[i][j][r] + bcol;
                if (mode == 2) {
                    z = fmaxf(z, 0.f) * (gc * inv) + bec;
                    z = lrelu(z);
                    sz += z; sq += z * z;
                } else if (mode == 3) {
                    float h = (float)A[(size_t)(row0 + r) * K + col];
                    z = (h - mu) * rs * gc + bec + z;
                    z = lrelu(z);
                }
                C[(size_t)(row0 + r) * ldc + col] = (bf16)z;
            }
        }
    }
    if (mode == 2) {
        for (int o = 32; o > 0; o >>= 1) { sz += __shfl_down(sz, o); sq += __shfl_down(sq, o); }
        __syncthreads();                     // mainloop LDS readers done
        float* rs_ = (float*)&As[0][0];
        float* rq_ = (float*)&Bs[0][0];
        if (lane == 0) { rs_[w] = sz; rq_[w] = sq; }
        __syncthreads();
        if (tid == 0) {
            atomicAdd(&stat[0], rs_[0] + rs_[1] + rs_[2] + rs_[3]);
            atomicAdd(&stat[1], rq_[0] + rq_[1] + rq_[2] + rq_[3]);
        }
    }
}

// ---------- MFMA GEMM (fp32 A), 128x128 tile, depth-4 pipeline (champion, CLOSED) ----------
__global__ __launch_bounds__(256, 1) void gemm_f32A(
    const float* __restrict__ A, const bf16* __restrict__ Bt,
    const float* __restrict__ bias, bf16* __restrict__ C, int K,
    const float* __restrict__ g, const float* __restrict__ be)
{
    __shared__ __align__(16) bf16 As[2][128 * SPAD];
    __shared__ __align__(16) bf16 Bs[2][128 * SPAD];
    const int tid = threadIdx.x;
    const int bm = blockIdx.y * 128, bn = blockIdx.x * 128;
    const int w = tid >> 6, lane = tid & 63;
    const int wm = (w & 1) * 64, wn = (w >> 1) * 64;
    const int lrow = lane & 15, lk8 = (lane >> 4) * 8;

    floatx4 acc[4][4];
#pragma unroll
    for (int i = 0; i < 4; i++)
#pragma unroll
        for (int j = 0; j < 4; j++) acc[i][j] = (floatx4){0.f, 0.f, 0.f, 0.f};

    const int r2 = tid >> 1, c2 = tid & 1;
    const float* gA = A + (size_t)(bm + r2) * K + c2 * 16;
    const bf16* gB = Bt + (size_t)(bn + r2) * K + c2 * 16;
    bf16* sA = &As[0][r2 * SPAD + c2 * 16];
    bf16* sB = &Bs[0][r2 * SPAD + c2 * 16];

    const int nk = K >> 5;   // 40
    float4 a[4][4];
    bf16x8 b[4][2];
#pragma unroll
    for (int u = 0; u < 4; u++) {
        const float* pa = gA + u * 32;
        a[u][0] = *(const float4*)(pa + 0);
        a[u][1] = *(const float4*)(pa + 4);
        a[u][2] = *(const float4*)(pa + 8);
        a[u][3] = *(const float4*)(pa + 12);
        const bf16* pb = gB + u * 32;
        b[u][0] = *(const bf16x8*)(pb + 0);
        b[u][1] = *(const bf16x8*)(pb + 8);
    }

    for (int it0 = 0; it0 < nk; it0 += 4) {
#pragma unroll
        for (int u = 0; u < 4; u++) {
            const int it = it0 + u;
            const int p = u & 1;
            const int po = p * 128 * SPAD;
            bf16x8 h0, h1;
            h0[0] = (bf16)a[u][0].x; h0[1] = (bf16)a[u][0].y; h0[2] = (bf16)a[u][0].z; h0[3] = (bf16)a[u][0].w;
            h0[4] = (bf16)a[u][1].x; h0[5] = (bf16)a[u][1].y; h0[6] = (bf16)a[u][1].z; h0[7] = (bf16)a[u][1].w;
            h1[0] = (bf16)a[u][2].x; h1[1] = (bf16)a[u][2].y; h1[2] = (bf16)a[u][2].z; h1[3] = (bf16)a[u][2].w;
            h1[4] = (bf16)a[u][3].x; h1[5] = (bf16)a[u][3].y; h1[6] = (bf16)a[u][3].z; h1[7] = (bf16)a[u][3].w;
            *(bf16x8*)(sA + po + 0) = h0;
            *(bf16x8*)(sA + po + 8) = h1;
            *(bf16x8*)(sB + po + 0) = b[u][0];
            *(bf16x8*)(sB + po + 8) = b[u][1];
            barrier_lds();
            if (it + 4 < nk) {
                const float* pa = gA + (it + 4) * 32;
                a[u][0] = *(const float4*)(pa + 0);
                a[u][1] = *(const float4*)(pa + 4);
                a[u][2] = *(const float4*)(pa + 8);
                a[u][3] = *(const float4*)(pa + 12);
                const bf16* pb = gB + (it + 4) * 32;
                b[u][0] = *(const bf16x8*)(pb + 0);
                b[u][1] = *(const bf16x8*)(pb + 8);
            }
            bf16x8 af[4], bfr[4];
#pragma unroll
            for (int i = 0; i < 4; i++) af[i] = *(const bf16x8*)&As[p][(wm + 16 * i + lrow) * SPAD + lk8];
#pragma unroll
            for (int j = 0; j < 4; j++) bfr[j] = *(const bf16x8*)&Bs[p][(wn + 16 * j + lrow) * SPAD + lk8];
#pragma unroll
            for (int i = 0; i < 4; i++)
#pragma unroll
                for (int j = 0; j < 4; j++)
                    acc[i][j] = __builtin_amdgcn_mfma_f32_16x16x32_bf16(af[i], bfr[j], acc[i][j], 0, 0, 0);
            barrier_lds();
        }
    }

    const float inv = rsqrtf(1.f + EPSC);
#pragma unroll
    for (int j = 0; j < 4; j++) {
        int col = bn + wn + 16 * j + lrow;
        float bcol = bias[col];
        float gc = g[col] * inv;
        float bec = be[col];
#pragma unroll
        for (int i = 0; i < 4; i++) {
            int row0 = bm + wm + 16 * i + (lane >> 4) * 4;
#pragma unroll
            for (int r = 0; r < 4; r++) {
                float z = fmaxf(acc[i][j][r] + bcol, 0.f) * gc + bec;
                C[(size_t)(row0 + r) * HID + col] = (bf16)z;
            }
        }
    }
}

// ---------- CSR build ----------
__global__ void hist_kernel(const int* __restrict__ ei, int* __restrict__ cnt) {
    int e = blockIdx.x * 256 + threadIdx.x;
    if (e >= EPE) return;
    int d = (e < N_EDGES) ? ei[N_EDGES + e] : (e - N_EDGES);
    atomicAdd(&cnt[d], 1);
}

__global__ __launch_bounds__(1024) void scan_kernel(const int* __restrict__ cnt,
                                                    int* __restrict__ roff, int* __restrict__ cursor,
                                                    const int* __restrict__ batch,
                                                    int* __restrict__ gstart) {
    __shared__ int wsum[16];
    int t = threadIdx.x;
    int base = t * 16;
    int local[16]; int s = 0;
#pragma unroll
    for (int i = 0; i < 16; i++) {
        int idx = base + i;
        int v = (idx < N_NODES) ? cnt[idx] : 0;
        local[i] = s; s += v;
    }
    int lane = t & 63, wid = t >> 6;
    int incl = s;
    for (int o = 1; o < 64; o <<= 1) { int v = __shfl_up(incl, o); if (lane >= o) incl += v; }
    if (lane == 63) wsum[wid] = incl;
    __syncthreads();
    if (t == 0) { int a = 0; for (int k = 0; k < 16; k++) { int v = wsum[k]; wsum[k] = a; a += v; } }
    __syncthreads();
    int texcl = incl - s + wsum[wid];
#pragma unroll
    for (int i = 0; i < 16; i++) {
        int idx = base + i;
        if (idx < N_NODES) { int o = texcl + local[i]; roff[idx] = o; cursor[idx] = o; }
    }
    if (t == 1023) roff[N_NODES] = texcl + s;
    if (t <= NG) {
        int lo = 0, hi = N_NODES;
        while (lo < hi) { int mid = (lo + hi) >> 1; if (batch[mid] < t) lo = mid + 1; else hi = mid; }
        gstart[t] = lo;
    }
}

__global__ void scatter_kernel(const int* __restrict__ ei, int* __restrict__ cursor,
                               int* __restrict__ esrc) {
    int e = blockIdx.x * 256 + threadIdx.x;
    if (e >= EPE) return;
    int s, d;
    if (e < N_EDGES) { s = ei[e]; d = ei[N_EDGES + e]; }
    else { s = d = e - N_EDGES; }
    int pos = atomicAdd(&cursor[d], 1);
    esrc[pos] = s;
}

// ---------- wave-per-dst GATv2: 4 edges/iter ----------
__global__ __launch_bounds__(256) void gat_wave(
    const bf16* __restrict__ XLR, const int* __restrict__ roff, const int* __restrict__ esrc,
    const float* __restrict__ att, const float* __restrict__ gbias, bf16* __restrict__ out)
{
    const int wid = threadIdx.x >> 6;
    const int lane = threadIdx.x & 63;
    const int d = blockIdx.x * 4 + wid;
    const int beg = roff[d], end = roff[d + 1];
    const int c0 = lane * 4;

    const unsigned int* xru = (const unsigned int*)(XLR + (size_t)d * 512 + 256 + c0);
    const unsigned int xr01 = xru[0], xr23 = xru[1];
    const float xr0 = bflo(xr01), xr1 = bfhi(xr01), xr2 = bflo(xr23), xr3 = bfhi(xr23);
    const float at0 = att[c0], at1 = att[c0 + 1], at2 = att[c0 + 2], at3 = att[c0 + 3];

    float m = -INFINITY, s = 0.f;
    float a0 = 0.f, a1 = 0.f, a2 = 0.f, a3 = 0.f;

    int e = beg;
    for (; e + 3 < end; e += 4) {
        int s0 = esrc[e], s1 = esrc[e + 1], s2 = esrc[e + 2], s3 = esrc[e + 3];
        const unsigned int* q0 = (const unsigned int*)(XLR + (size_t)s0 * 512 + c0);
        const unsigned int* q1 = (const unsigned int*)(XLR + (size_t)s1 * 512 + c0);
        const unsigned int* q2 = (const unsigned int*)(XLR + (size_t)s2 * 512 + c0);
        const unsigned int* q3 = (const unsigned int*)(XLR + (size_t)s3 * 512 + c0);
        unsigned int u01 = q0[0], u23 = q0[1];
        unsigned int v01 = q1[0], v23 = q1[1];
        unsigned int w01 = q2[0], w23 = q2[1];
        unsigned int x01 = q3[0], x23 = q3[1];
        float x0 = bflo(u01), x1 = bfhi(u01), x2 = bflo(u23), x3 = bfhi(u23);
        float y0 = bflo(v01), y1 = bfhi(v01), y2 = bflo(v23), y3 = bfhi(v23);
        float z0 = bflo(w01), z1 = bfhi(w01), z2 = bflo(w23), z3 = bfhi(w23);
        float t0 = bflo(x01), t1 = bfhi(x01), t2 = bflo(x23), t3 = bfhi(x23);
        float p0 = lrelu(x0 + xr0) * at0 + lrelu(x1 + xr1) * at1
                 + lrelu(x2 + xr2) * at2 + lrelu(x3 + xr3) * at3;
        float p1 = lrelu(y0 + xr0) * at0 + lrelu(y1 + xr1) * at1
                 + lrelu(y2 + xr2) * at2 + lrelu(y3 + xr3) * at3;
        float p2 = lrelu(z0 + xr0) * at0 + lrelu(z1 + xr1) * at1
                 + lrelu(z2 + xr2) * at2 + lrelu(z3 + xr3) * at3;
        float p3 = lrelu(t0 + xr0) * at0 + lrelu(t1 + xr1) * at1
                 + lrelu(t2 + xr2) * at2 + lrelu(t3 + xr3) * at3;
        p0 += __shfl_xor(p0, 1);  p1 += __shfl_xor(p1, 1);
        p2 += __shfl_xor(p2, 1);  p3 += __shfl_xor(p3, 1);
        p0 += __shfl_xor(p0, 2);  p1 += __shfl_xor(p1, 2);
        p2 += __shfl_xor(p2, 2);  p3 += __shfl_xor(p3, 2);
        p0 += __shfl_xor(p0, 4);  p1 += __shfl_xor(p1, 4);
        p2 += __shfl_xor(p2, 4);  p3 += __shfl_xor(p3, 4);
        float mn = fmaxf(fmaxf(m, fmaxf(p0, p1)), fmaxf(p2, p3));
        float rsc = __expf(m - mn);              // first iter: exp(-inf)=0
        float w0 = __expf(p0 - mn);
        float w1 = __expf(p1 - mn);
        float w2 = __expf(p2 - mn);
        float w3 = __expf(p3 - mn);
        s = s * rsc + (w0 + w1) + (w2 + w3);
        a0 = a0 * rsc + (w0 * x0 + w1 * y0) + (w2 * z0 + w3 * t0);
        a1 = a1 * rsc + (w0 * x1 + w1 * y1) + (w2 * z1 + w3 * t1);
        a2 = a2 * rsc + (w0 * x2 + w1 * y2) + (w2 * z2 + w3 * t2);
        a3 = a3 * rsc + (w0 * x3 + w1 * y3) + (w2 * z3 + w3 * t3);
        m = mn;
    }
    for (; e < end; ++e) {                       // tail (0-3 edges)
        int s0 = esrc[e];
        const unsigned int* q0 = (const unsigned int*)(XLR + (size_t)s0 * 512 + c0);
        unsigned int u01 = q0[0], u23 = q0[1];
        float x0 = bflo(u01), x1 = bfhi(u01), x2 = bflo(u23), x3 = bfhi(u23);
        float p = lrelu(x0 + xr0) * at0 + lrelu(x1 + xr1) * at1
                + lrelu(x2 + xr2) * at2 + lrelu(x3 + xr3) * at3;
        p += __shfl_xor(p, 1);
        p += __shfl_xor(p, 2);
        p += __shfl_xor(p, 4);
        float mn = fmaxf(m, p);
        float rsc = __expf(m - mn);
        float wgt = __expf(p - mn);
        s = s * rsc + wgt;
        a0 = a0 * rsc + wgt * x0;
        a1 = a1 * rsc + wgt * x1;
        a2 = a2 * rsc + wgt * x2;
        a3 = a3 * rsc + wgt * x3;
        m = mn;
    }

    const float rinv = 1.f / (s + 1e-16f);
    float v0 = gbias[c0]     + a0 * rinv;
    float v1 = gbias[c0 + 1] + a1 * rinv;
    float v2 = gbias[c0 + 2] + a2 * rinv;
    float v3 = gbias[c0 + 3] + a3 * rinv;
    unsigned int* op = (unsigned int*)(out + (size_t)d * HID + c0);
    op[0] = bfpack(v0, v1);
    op[1] = bfpack(v2, v3);
}

// ---------- wave-per-dst GIN gather (4 gathers in flight) + zero stat ----------
__global__ __launch_bounds__(256) void gin_wave(
    const bf16* __restrict__ H, const int* __restrict__ roff,
    const int* __restrict__ esrc, bf16* __restrict__ U, float* __restrict__ stat)
{
    if (blockIdx.x == 0 && threadIdx.x == 0) { stat[0] = 0.f; stat[1] = 0.f; }
    const int wid = threadIdx.x >> 6;
    const int lane = threadIdx.x & 63;
    const int d = blockIdx.x * 4 + wid;
    const int beg = roff[d], end = roff[d + 1];
    const int c0 = lane * 4;

    float a0 = 0.f, a1 = 0.f, a2 = 0.f, a3 = 0.f;
    int e = beg;
    for (; e + 3 < end; e += 4) {
        int s0 = esrc[e], s1 = esrc[e + 1], s2 = esrc[e + 2], s3 = esrc[e + 3];
        const unsigned int* p0 = (const unsigned int*)(H + (size_t)s0 * HID + c0);
        const unsigned int* p1 = (const unsigned int*)(H + (size_t)s1 * HID + c0);
        const unsigned int* p2 = (const unsigned int*)(H + (size_t)s2 * HID + c0);
        const unsigned int* p3 = (const unsigned int*)(H + (size_t)s3 * HID + c0);
        unsigned int u01 = p0[0], u23 = p0[1];
        unsigned int v01 = p1[0], v23 = p1[1];
        unsigned int w01 = p2[0], w23 = p2[1];
        unsigned int x01 = p3[0], x23 = p3[1];
        a0 += (bflo(u01) + bflo(v01)) + (bflo(w01) + bflo(x01));
        a1 += (bfhi(u01) + bfhi(v01)) + (bfhi(w01) + bfhi(x01));
        a2 += (bflo(u23) + bflo(v23)) + (bflo(w23) + bflo(x23));
        a3 += (bfhi(u23) + bfhi(v23)) + (bfhi(w23) + bfhi(x23));
    }
    for (; e < end; ++e) {
        const unsigned int* p0 = (const unsigned int*)(H + (size_t)esrc[e] * HID + c0);
        unsigned int u01 = p0[0], u23 = p0[1];
        a0 += bflo(u01); a1 += bfhi(u01); a2 += bflo(u23); a3 += bfhi(u23);
    }
    unsigned int* up = (unsigned int*)(U + (size_t)d * HID + c0);
    up[0] = bfpack(a0, a1);
    up[1] = bfpack(a2, a3);
}

// ---------- pooling ----------
__global__ __launch_bounds__(256) void pool_gate_kernel(const bf16* __restrict__ t,
    const float* __restrict__ W2, const float* __restrict__ b2, float* __restrict__ gate)
{
    int n = blockIdx.x * 4 + (threadIdx.x >> 6);
    int lane = threadIdx.x & 63;
    const bf16* p = t + (size_t)n * HID + lane * 4;
    float4 w = *(const float4*)(W2 + lane * 4);
    float s = tanhf((float)p[0]) * w.x + tanhf((float)p[1]) * w.y
            + tanhf((float)p[2]) * w.z + tanhf((float)p[3]) * w.w;
    for (int o = 32; o > 0; o >>= 1) s += __shfl_down(s, o);
    if (lane == 0) gate[n] = s + b2[0];
}

// pool softmax stats; ALSO zeroes emb[g] (emb_accum runs after in stream order)
__global__ __launch_bounds__(256) void pool_stats_kernel(
    float* __restrict__ gate, const int* __restrict__ gstart, float* __restrict__ emb)
{
    int g = blockIdx.x, t = threadIdx.x;
    emb[g * HID + t] = 0.f;
    int lo = gstart[g], hi = gstart[g + 1];
    __shared__ float red[256];
    float m = -INFINITY;
    for (int n = lo + t; n < hi; n += 256) m = fmaxf(m, gate[n]);
    red[t] = m; __syncthreads();
    for (int st = 128; st > 0; st >>= 1) { if (t < st) red[t] = fmaxf(red[t], red[t + st]); __syncthreads(); }
    m = red[0]; __syncthreads();
    float s = 0.f;
    for (int n = lo + t; n < hi; n += 256) s += __expf(gate[n] - m);
    red[t] = s; __syncthreads();
    for (int st = 128; st > 0; st >>= 1) { if (t < st) red[t] += red[t + st]; __syncthreads(); }
    float sinv = 1.f / (red[0] + 1e-16f);
    for (int n = lo + t; n < hi; n += 256) gate[n] = __expf(gate[n] - m) * sinv;
}

__global__ __launch_bounds__(256) void emb_accum_kernel(
    const float* __restrict__ a, const int* __restrict__ batch,
    const bf16* __restrict__ h, float* __restrict__ emb)
{
    int n0 = blockIdx.x * 32, t = threadIdx.x;
    int cur = batch[n0]; float acc = 0.f;
    for (int j = 0; j < 32; j++) {
        int n = n0 + j;
        int b = batch[n];
        if (b != cur) { atomicAdd(&emb[cur * HID + t], acc); cur = b; acc = 0.f; }
        acc += a[n] * (float)h[(size_t)n * HID + t];
    }
    atomicAdd(&emb[cur * HID + t], acc);
}

// ---------- label heads (R9-proven original: 512 blocks) ----------
__global__ __launch_bounds__(256) void heads_kernel(
    const float* __restrict__ emb, const float* __restrict__ W1, const float* __restrict__ b1,
    const float* __restrict__ hg, const float* __restrict__ hbe, const float* __restrict__ W2,
    const float* __restrict__ b2, float* __restrict__ out)
{
    int o = blockIdx.x;
    int g0 = blockIdx.y * 4;
    int k = threadIdx.x;
    __shared__ float se[4][HID];
    __shared__ float red[256];
#pragma unroll
    for (int j = 0; j < 4; j++) se[j][k] = emb[(g0 + j) * HID + k];
    __syncthreads();
    const float* w1p = W1 + (size_t)o * HID * HID + k;
    float zb = b1[o * HID + k];
    float z0 = zb, z1 = zb, z2 = zb, z3 = zb;
#pragma unroll 8
    for (int d = 0; d < HID; d++) {
        float w = w1p[(size_t)d * HID];
        z0 = fmaf(se[0][d], w, z0);
        z1 = fmaf(se[1][d], w, z1);
        z2 = fmaf(se[2][d], w, z2);
        z3 = fmaf(se[3][d], w, z3);
    }
    const float gk = hg[o * HID + k] * rsqrtf(1.f + EPSC);
    const float bek = hbe[o * HID + k];
    const float w2 = W2[o * HID + k];
    const float b2o = b2[o];
    float zz[4] = {z0, z1, z2, z3};
#pragma unroll
    for (int j = 0; j < 4; j++) {
        float z = zz[j];
        float sil = z / (1.f + expf(-z));
        red[k] = (sil * gk + bek) * w2;
        __syncthreads();
        for (int st = 128; st > 0; st >>= 1) { if (k < st) red[k] += red[k + st]; __syncthreads(); }
        if (k == 0) out[(g0 + j) * NO + o] = red[0] + b2o;
        __syncthreads();
    }
}

extern "C" void kernel_launch(void* const* d_in, const int* in_sizes, int n_in,
                              void* d_out, int out_size, void* d_ws, size_t ws_size,
                              hipStream_t stream) {
    const float* x        = (const float*)d_in[0];
    const int*   ei       = (const int*)  d_in[1];
    const int*   batch    = (const int*)  d_in[2];
    const float* fp_W     = (const float*)d_in[3];
    const float* fp_b     = (const float*)d_in[4];
    const float* fp_g     = (const float*)d_in[5];
    const float* fp_be    = (const float*)d_in[6];
    const float* gat_Wl   = (const float*)d_in[7];
    const float* gat_bl   = (const float*)d_in[8];
    const float* gat_Wr   = (const float*)d_in[9];
    const float* gat_br   = (const float*)d_in[10];
    const float* gat_att  = (const float*)d_in[11];
    const float* gat_bias = (const float*)d_in[12];
    const float* gin_W    = (const float*)d_in[13];
    const float* gin_b    = (const float*)d_in[14];
    const float* gin_g    = (const float*)d_in[15];
    const float* gin_be   = (const float*)d_in[16];
    const float* ln_g     = (const float*)d_in[17];
    const float* ln_b     = (const float*)d_in[18];
    const float* res_W    = (const float*)d_in[19];
    const float* res_b    = (const float*)d_in[20];
    const float* pool_W1  = (const float*)d_in[21];
    const float* pool_b1  = (const float*)d_in[22];
    const float* pool_W2  = (const float*)d_in[23];
    const float* pool_b2  = (const float*)d_in[24];
    const float* head_W1  = (const float*)d_in[25];
    const float* head_b1  = (const float*)d_in[26];
    const float* head_g   = (const float*)d_in[27];
    const float* head_be  = (const float*)d_in[28];
    const float* head_W2  = (const float*)d_in[29];
    const float* head_b2  = (const float*)d_in[30];
    float* out = (float*)d_out;

    char* base = (char*)d_ws;
    size_t off = 0;
    auto alloc = [&](size_t bytes) -> char* {
        char* p = base + off; off += (bytes + 255) & ~(size_t)255; return p;
    };
    int*   esrc   = (int*)  alloc((size_t)EPE * 4);
    int*   cnt    = (int*)  alloc((size_t)N_NODES * 4);
    int*   roff   = (int*)  alloc((size_t)(N_NODES + 1) * 4);
    int*   cursor = (int*)  alloc((size_t)N_NODES * 4);
    float* gate   = (float*)alloc((size_t)N_NODES * 4);
    int*   gstart = (int*)  alloc((NG + 1) * 4);
    float* emb    = (float*)alloc(NG * HID * 4);
    float* stat   = (float*)alloc(8);
    bf16*  Hb0    = (bf16*) alloc((size_t)N_NODES * HID * 2);
    bf16*  Hb1    = (bf16*) alloc((size_t)N_NODES * HID * 2);
    bf16*  XLR    = (bf16*) alloc((size_t)N_NODES * 512 * 2);
    bf16*  fpWt   = (bf16*) alloc((size_t)DIN * HID * 2);
    bf16*  wlrT0  = (bf16*) alloc((size_t)512 * HID * 2);
    bf16*  wlrT1  = (bf16*) alloc((size_t)512 * HID * 2);
    bf16*  gwT    = (bf16*) alloc((size_t)2 * HID * HID * 2);
    bf16*  rwT    = (bf16*) alloc((size_t)2 * HID * HID * 2);
    bf16*  pwT    = (bf16*) alloc((size_t)HID * HID * 2);
    bf16*  Ub     = XLR;
    bf16*  wlrT[2] = { wlrT0, wlrT1 };

    // ---- fused weight conversion (1 launch) ----
    wconv_all<<<3584, 256, 0, stream>>>(fp_W, gat_Wl, gat_Wr, gin_W, res_W, pool_W1,
                                        fpWt, wlrT0, wlrT1, gwT, rwT, pwT);

    // ---- CSR build (+ graph boundaries fused into scan) ----
    hipMemsetAsync(cnt, 0, N_NODES * sizeof(int), stream);
    hist_kernel<<<(EPE + 255) / 256, 256, 0, stream>>>(ei, cnt);
    scan_kernel<<<1, 1024, 0, stream>>>(cnt, roff, cursor, batch, gstart);
    scatter_kernel<<<(EPE + 255) / 256, 256, 0, stream>>>(ei, cursor, esrc);

    // ---- feature projection (128x128 tiles, depth-4, champion config) ----
    dim3 gridF(2, 125);
    dim3 g128_256(2, 125);       // 128x128 tiles, 256 cols
    dim3 g128_512(4, 125);       // 128x128 tiles, 512 cols
    gemm_f32A<<<gridF, 256, 0, stream>>>(x, fpWt, fp_b, Hb0, DIN, fp_g, fp_be);

    bf16* hcur = Hb0;
    bf16* hoth = Hb1;
    for (int i = 0; i < 2; i++) {
        // xl|xr
        gemm128<<<g128_512, 256, 0, stream>>>(hcur, wlrT[i], gat_bl + i * HID, gat_br + i * HID,
                                              XLR, HID, 512, 0, nullptr, nullptr, nullptr);
        // GAT -> hoth (wave-per-dst, 4 edges/iter)
        gat_wave<<<N_NODES / 4, 256, 0, stream>>>(XLR, roff, esrc, gat_att + i * HEADS * CPH,
                                                  gat_bias + i * HID, hoth);
        // GIN aggregate -> Ub (wave-per-dst, 4 gathers/iter), zeroes stat
        gin_wave<<<N_NODES / 4, 256, 0, stream>>>(hoth, roff, esrc, Ub, stat);
        // h_gin = leaky(BN(relu(u@W+b))) -> hcur, stats atomically into stat
        gemm128<<<g128_256, 256, 0, stream>>>(Ub, gwT + (size_t)i * HID * HID, gin_b + i * HID,
                                              nullptr, hcur, HID, HID, 2,
                                              gin_g + i * HID, gin_be + i * HID, stat);
        // h = leaky(LN(h_gin) + h_gin@res_W + res_b) -> hoth
        gemm128<<<g128_256, 256, 0, stream>>>(hcur, rwT + (size_t)i * HID * HID, res_b + i * HID,
                                              nullptr, hoth, HID, HID, 3,
                                              ln_g + i * HID, ln_b + i * HID, stat);
        bf16* tmp = hcur; hcur = hoth; hoth = tmp;
    }

    // ---- global attention pooling ----
    gemm128<<<g128_256, 256, 0, stream>>>(hcur, pwT, pool_b1, nullptr, hoth, HID, HID, 0,
                                          nullptr, nullptr, nullptr);
    pool_gate_kernel<<<N_NODES / 4, 256, 0, stream>>>(hoth, pool_W2, pool_b2, gate);
    pool_stats_kernel<<<NG, 256, 0, stream>>>(gate, gstart, emb);
    emb_accum_kernel<<<N_NODES / 32, 256, 0, stream>>>(gate, batch, hcur, emb);

    // ---- label heads (R9-proven original) ----
    dim3 hgrid(NO, 8);
    heads_kernel<<<hgrid, 256, 0, stream>>>(emb, head_W1, head_b1, head_g, head_be,
                                            head_W2, head_b2, out);
}

// Round 14
// 515.162 us; speedup vs baseline: 1.1576x; 1.0169x over previous
//
#include <hip/hip_runtime.h>
#include <math.h>

#define N_NODES 16000
#define N_EDGES 256000
#define EPE (N_EDGES + N_NODES)
#define DIN 1280
#define HID 256
#define HEADS 8
#define CPH 32
#define NG 32
#define NO 64
#define EPSC 1e-5f
#define SPAD 40     // GEMM LDS row stride (bf16): 80 B, 16B-aligned

typedef __bf16 bf16;
typedef __attribute__((ext_vector_type(8))) __bf16 bf16x8;
typedef __attribute__((ext_vector_type(4))) float floatx4;

__device__ __forceinline__ float lrelu(float v) { return v > 0.f ? v : 0.2f * v; }
__device__ __forceinline__ float bflo(unsigned int u) { return __uint_as_float(u << 16); }
__device__ __forceinline__ float bfhi(unsigned int u) { return __uint_as_float(u & 0xffff0000u); }
__device__ __forceinline__ unsigned int bfpack(float x, float y) {
    bf16 b0 = (bf16)x, b1 = (bf16)y;
    return ((unsigned int)*(unsigned short*)&b0) | (((unsigned int)*(unsigned short*)&b1) << 16);
}

// LDS-only barrier (no vmcnt drain): safe in loops with no global stores.
__device__ __forceinline__ void barrier_lds() {
    asm volatile("s_waitcnt lgkmcnt(0)" ::: "memory");
    __builtin_amdgcn_s_barrier();
}

// ---------- fused weight transpose/convert (1 launch) + cnt/gate zeroing ----------
__global__ __launch_bounds__(256) void wconv_all(
    const float* __restrict__ fp_W, const float* __restrict__ gat_Wl,
    const float* __restrict__ gat_Wr, const float* __restrict__ gin_W,
    const float* __restrict__ res_W, const float* __restrict__ pool_W1,
    bf16* __restrict__ fpWt, bf16* __restrict__ wlrT0, bf16* __restrict__ wlrT1,
    bf16* __restrict__ gwT, bf16* __restrict__ rwT, bf16* __restrict__ pwT,
    int* __restrict__ cnt, float* __restrict__ gate)
{
    int idx = blockIdx.x * 256 + threadIdx.x;
    if (idx < N_NODES) { cnt[idx] = 0; gate[idx] = 0.f; }   // stream-ordered before hist / pool
    if (idx < 327680) {                       // fpWt [256][1280] <- fp_W [1280][256]
        int n = idx / 1280, k = idx - n * 1280;
        fpWt[idx] = (bf16)fp_W[k * 256 + n];
    } else if (idx < 458752) {                // wlrT0 [512][256]
        int r = idx - 327680; int n = r >> 8, k = r & 255;
        wlrT0[r] = (bf16)(n < 256 ? gat_Wl[k * 256 + n] : gat_Wr[k * 256 + (n - 256)]);
    } else if (idx < 589824) {                // wlrT1 [512][256]
        int r = idx - 458752; int n = r >> 8, k = r & 255;
        wlrT1[r] = (bf16)(n < 256 ? gat_Wl[65536 + k * 256 + n]
                                  : gat_Wr[65536 + k * 256 + (n - 256)]);
    } else if (idx < 720896) {                // gwT 2x[256][256]
        int r = idx - 589824; int l = r >> 16, rr = r & 65535;
        int n = rr >> 8, k = rr & 255;
        gwT[r] = (bf16)gin_W[l * 65536 + k * 256 + n];
    } else if (idx < 851968) {                // rwT 2x[256][256]
        int r = idx - 720896; int l = r >> 16, rr = r & 65535;
        int n = rr >> 8, k = rr & 255;
        rwT[r] = (bf16)res_W[l * 65536 + k * 256 + n];
    } else {                                  // pwT [256][256]
        int r = idx - 851968; int n = r >> 8, k = r & 255;
        pwT[r] = (bf16)pool_W1[k * 256 + n];
    }
}

// ---------- MFMA GEMM (bf16), 128x128 tile, 4-deep register pipeline ----------
// mode 0: +bias (bias2 for cols >= HID)
// mode 2: +bias,relu,bn,leaky AND atomicAdd block stats (sum,sumsq) into stat[0..1]
// mode 3: residual+LN: out = lrelu( (h-mu)*rs*g + b + (acc+bias) ), h reloaded from A
// mode 4: fused pooling gate: atomicAdd(gate[row], sum_col tanh(acc+bias)*W2[col]);
//         g = pool_W2, stat = gate, C not written (pool_b2 cancels in softmax).
__global__ __launch_bounds__(256) void gemm128(
    const bf16* __restrict__ A, const bf16* __restrict__ Bt,
    const float* __restrict__ bias, const float* __restrict__ bias2,
    bf16* __restrict__ C, int K, int ldc, int mode,
    const float* __restrict__ g, const float* __restrict__ be,
    float* __restrict__ stat)
{
    __shared__ __align__(16) bf16 As[2][128 * SPAD];
    __shared__ __align__(16) bf16 Bs[2][128 * SPAD];
    const int tid = threadIdx.x;
    const int bm = blockIdx.y * 128, bn = blockIdx.x * 128;
    const int w = tid >> 6, lane = tid & 63;
    const int wm = (w & 1) * 64, wn = (w >> 1) * 64;
    const int lrow = lane & 15, lk8 = (lane >> 4) * 8;

    floatx4 acc[4][4];
#pragma unroll
    for (int i = 0; i < 4; i++)
#pragma unroll
        for (int j = 0; j < 4; j++) acc[i][j] = (floatx4){0.f, 0.f, 0.f, 0.f};

    const int r2 = tid >> 1, c2 = tid & 1;
    const bf16* gA = A + (size_t)(bm + r2) * K + c2 * 16;
    const bf16* gB = Bt + (size_t)(bn + r2) * K + c2 * 16;
    bf16* sA = &As[0][r2 * SPAD + c2 * 16];
    bf16* sB = &Bs[0][r2 * SPAD + c2 * 16];

    const int nk = K >> 5;   // 8
    bf16x8 a[4][2], b[4][2];
#pragma unroll
    for (int u = 0; u < 4; u++) {
        const bf16* pa = gA + u * 32;
        a[u][0] = *(const bf16x8*)(pa + 0);
        a[u][1] = *(const bf16x8*)(pa + 8);
        const bf16* pb = gB + u * 32;
        b[u][0] = *(const bf16x8*)(pb + 0);
        b[u][1] = *(const bf16x8*)(pb + 8);
    }

    for (int it0 = 0; it0 < nk; it0 += 4) {
#pragma unroll
        for (int u = 0; u < 4; u++) {
            const int it = it0 + u;
            const int p = u & 1;
            const int po = p * 128 * SPAD;
            *(bf16x8*)(sA + po + 0) = a[u][0];
            *(bf16x8*)(sA + po + 8) = a[u][1];
            *(bf16x8*)(sB + po + 0) = b[u][0];
            *(bf16x8*)(sB + po + 8) = b[u][1];
            barrier_lds();
            if (it + 4 < nk) {
                const bf16* pa = gA + (it + 4) * 32;
                a[u][0] = *(const bf16x8*)(pa + 0);
                a[u][1] = *(const bf16x8*)(pa + 8);
                const bf16* pb = gB + (it + 4) * 32;
                b[u][0] = *(const bf16x8*)(pb + 0);
                b[u][1] = *(const bf16x8*)(pb + 8);
            }
            bf16x8 af[4], bfr[4];
#pragma unroll
            for (int i = 0; i < 4; i++) af[i] = *(const bf16x8*)&As[p][(wm + 16 * i + lrow) * SPAD + lk8];
#pragma unroll
            for (int j = 0; j < 4; j++) bfr[j] = *(const bf16x8*)&Bs[p][(wn + 16 * j + lrow) * SPAD + lk8];
#pragma unroll
            for (int i = 0; i < 4; i++)
#pragma unroll
                for (int j = 0; j < 4; j++)
                    acc[i][j] = __builtin_amdgcn_mfma_f32_16x16x32_bf16(af[i], bfr[j], acc[i][j], 0, 0, 0);
            barrier_lds();
        }
    }

    if (mode == 4) {
        // gate partial: sum over this block's 128 cols of tanh(z)*W2[col], per row.
        const int rbase = bm + wm + (lane >> 4) * 4;
#pragma unroll
        for (int i = 0; i < 4; i++) {
#pragma unroll
            for (int r = 0; r < 4; r++) {
                float part = 0.f;
#pragma unroll
                for (int j = 0; j < 4; j++) {
                    int col = bn + wn + 16 * j + lrow;
                    float z = acc[i][j][r] + bias[col];
                    part += tanhf(z) * g[col];
                }
                part += __shfl_xor(part, 1);
                part += __shfl_xor(part, 2);
                part += __shfl_xor(part, 4);
                part += __shfl_xor(part, 8);
                if ((lane & 15) == 0)
                    atomicAdd(&stat[rbase + 16 * i + r], part);
            }
        }
        return;
    }

    const float inv = rsqrtf(1.f + EPSC);
    float mu = 0.f, rs = 0.f;
    if (mode == 3) {
        const float inv_n = 1.f / (float)((size_t)N_NODES * HID);
        mu = stat[0] * inv_n;
        float var = stat[1] * inv_n - mu * mu;
        rs = 1.f / (sqrtf(fmaxf(var, 0.f)) + EPSC);
    }
    float sz = 0.f, sq = 0.f;
#pragma unroll
    for (int j = 0; j < 4; j++) {
        int col = bn + wn + 16 * j + lrow;
        float bcol = (col < HID) ? bias[col] : bias2[col - HID];
        float gc = (mode >= 2) ? g[col] : 0.f;
        float bec = (mode >= 2) ? be[col] : 0.f;
#pragma unroll
        for (int i = 0; i < 4; i++) {
            int row0 = bm + wm + 16 * i + (lane >> 4) * 4;
#pragma unroll
            for (int r = 0; r < 4; r++) {
                float z = acc[i][j][r] + bcol;
                if (mode == 2) {
                    z = fmaxf(z, 0.f) * (gc * inv) + bec;
                    z = lrelu(z);
                    sz += z; sq += z * z;
                } else if (mode == 3) {
                    float h = (float)A[(size_t)(row0 + r) * K + col];
                    z = (h - mu) * rs * gc + bec + z;
                    z = lrelu(z);
                }
                C[(size_t)(row0 + r) * ldc + col] = (bf16)z;
            }
        }
    }
    if (mode == 2) {
        for (int o = 32; o > 0; o >>= 1) { sz += __shfl_down(sz, o); sq += __shfl_down(sq, o); }
        __syncthreads();                     // mainloop LDS readers done
        float* rs_ = (float*)&As[0][0];
        float* rq_ = (float*)&Bs[0][0];
        if (lane == 0) { rs_[w] = sz; rq_[w] = sq; }
        __syncthreads();
        if (tid == 0) {
            atomicAdd(&stat[0], rs_[0] + rs_[1] + rs_[2] + rs_[3]);
            atomicAdd(&stat[1], rq_[0] + rq_[1] + rq_[2] + rq_[3]);
        }
    }
}

// ---------- MFMA GEMM (fp32 A), 128x128 tile, depth-4 pipeline (champion, CLOSED) ----------
__global__ __launch_bounds__(256, 1) void gemm_f32A(
    const float* __restrict__ A, const bf16* __restrict__ Bt,
    const float* __restrict__ bias, bf16* __restrict__ C, int K,
    const float* __restrict__ g, const float* __restrict__ be)
{
    __shared__ __align__(16) bf16 As[2][128 * SPAD];
    __shared__ __align__(16) bf16 Bs[2][128 * SPAD];
    const int tid = threadIdx.x;
    const int bm = blockIdx.y * 128, bn = blockIdx.x * 128;
    const int w = tid >> 6, lane = tid & 63;
    const int wm = (w & 1) * 64, wn = (w >> 1) * 64;
    const int lrow = lane & 15, lk8 = (lane >> 4) * 8;

    floatx4 acc[4][4];
#pragma unroll
    for (int i = 0; i < 4; i++)
#pragma unroll
        for (int j = 0; j < 4; j++) acc[i][j] = (floatx4){0.f, 0.f, 0.f, 0.f};

    const int r2 = tid >> 1, c2 = tid & 1;
    const float* gA = A + (size_t)(bm + r2) * K + c2 * 16;
    const bf16* gB = Bt + (size_t)(bn + r2) * K + c2 * 16;
    bf16* sA = &As[0][r2 * SPAD + c2 * 16];
    bf16* sB = &Bs[0][r2 * SPAD + c2 * 16];

    const int nk = K >> 5;   // 40
    float4 a[4][4];
    bf16x8 b[4][2];
#pragma unroll
    for (int u = 0; u < 4; u++) {
        const float* pa = gA + u * 32;
        a[u][0] = *(const float4*)(pa + 0);
        a[u][1] = *(const float4*)(pa + 4);
        a[u][2] = *(const float4*)(pa + 8);
        a[u][3] = *(const float4*)(pa + 12);
        const bf16* pb = gB + u * 32;
        b[u][0] = *(const bf16x8*)(pb + 0);
        b[u][1] = *(const bf16x8*)(pb + 8);
    }

    for (int it0 = 0; it0 < nk; it0 += 4) {
#pragma unroll
        for (int u = 0; u < 4; u++) {
            const int it = it0 + u;
            const int p = u & 1;
            const int po = p * 128 * SPAD;
            bf16x8 h0, h1;
            h0[0] = (bf16)a[u][0].x; h0[1] = (bf16)a[u][0].y; h0[2] = (bf16)a[u][0].z; h0[3] = (bf16)a[u][0].w;
            h0[4] = (bf16)a[u][1].x; h0[5] = (bf16)a[u][1].y; h0[6] = (bf16)a[u][1].z; h0[7] = (bf16)a[u][1].w;
            h1[0] = (bf16)a[u][2].x; h1[1] = (bf16)a[u][2].y; h1[2] = (bf16)a[u][2].z; h1[3] = (bf16)a[u][2].w;
            h1[4] = (bf16)a[u][3].x; h1[5] = (bf16)a[u][3].y; h1[6] = (bf16)a[u][3].z; h1[7] = (bf16)a[u][3].w;
            *(bf16x8*)(sA + po + 0) = h0;
            *(bf16x8*)(sA + po + 8) = h1;
            *(bf16x8*)(sB + po + 0) = b[u][0];
            *(bf16x8*)(sB + po + 8) = b[u][1];
            barrier_lds();
            if (it + 4 < nk) {
                const float* pa = gA + (it + 4) * 32;
                a[u][0] = *(const float4*)(pa + 0);
                a[u][1] = *(const float4*)(pa + 4);
                a[u][2] = *(const float4*)(pa + 8);
                a[u][3] = *(const float4*)(pa + 12);
                const bf16* pb = gB + (it + 4) * 32;
                b[u][0] = *(const bf16x8*)(pb + 0);
                b[u][1] = *(const bf16x8*)(pb + 8);
            }
            bf16x8 af[4], bfr[4];
#pragma unroll
            for (int i = 0; i < 4; i++) af[i] = *(const bf16x8*)&As[p][(wm + 16 * i + lrow) * SPAD + lk8];
#pragma unroll
            for (int j = 0; j < 4; j++) bfr[j] = *(const bf16x8*)&Bs[p][(wn + 16 * j + lrow) * SPAD + lk8];
#pragma unroll
            for (int i = 0; i < 4; i++)
#pragma unroll
                for (int j = 0; j < 4; j++)
                    acc[i][j] = __builtin_amdgcn_mfma_f32_16x16x32_bf16(af[i], bfr[j], acc[i][j], 0, 0, 0);
            barrier_lds();
        }
    }

    const float inv = rsqrtf(1.f + EPSC);
#pragma unroll
    for (int j = 0; j < 4; j++) {
        int col = bn + wn + 16 * j + lrow;
        float bcol = bias[col];
        float gc = g[col] * inv;
        float bec = be[col];
#pragma unroll
        for (int i = 0; i < 4; i++) {
            int row0 = bm + wm + 16 * i + (lane >> 4) * 4;
#pragma unroll
            for (int r = 0; r < 4; r++) {
                float z = fmaxf(acc[i][j][r] + bcol, 0.f) * gc + bec;
                C[(size_t)(row0 + r) * HID + col] = (bf16)z;
            }
        }
    }
}

// ---------- CSR build ----------
__global__ void hist_kernel(const int* __restrict__ ei, int* __restrict__ cnt) {
    int e = blockIdx.x * 256 + threadIdx.x;
    if (e >= EPE) return;
    int d = (e < N_EDGES) ? ei[N_EDGES + e] : (e - N_EDGES);
    atomicAdd(&cnt[d], 1);
}

__global__ __launch_bounds__(1024) void scan_kernel(const int* __restrict__ cnt,
                                                    int* __restrict__ roff, int* __restrict__ cursor,
                                                    const int* __restrict__ batch,
                                                    int* __restrict__ gstart) {
    __shared__ int wsum[16];
    int t = threadIdx.x;
    int base = t * 16;
    int local[16]; int s = 0;
#pragma unroll
    for (int i = 0; i < 16; i++) {
        int idx = base + i;
        int v = (idx < N_NODES) ? cnt[idx] : 0;
        local[i] = s; s += v;
    }
    int lane = t & 63, wid = t >> 6;
    int incl = s;
    for (int o = 1; o < 64; o <<= 1) { int v = __shfl_up(incl, o); if (lane >= o) incl += v; }
    if (lane == 63) wsum[wid] = incl;
    __syncthreads();
    if (t == 0) { int a = 0; for (int k = 0; k < 16; k++) { int v = wsum[k]; wsum[k] = a; a += v; } }
    __syncthreads();
    int texcl = incl - s + wsum[wid];
#pragma unroll
    for (int i = 0; i < 16; i++) {
        int idx = base + i;
        if (idx < N_NODES) { int o = texcl + local[i]; roff[idx] = o; cursor[idx] = o; }
    }
    if (t == 1023) roff[N_NODES] = texcl + s;
    if (t <= NG) {
        int lo = 0, hi = N_NODES;
        while (lo < hi) { int mid = (lo + hi) >> 1; if (batch[mid] < t) lo = mid + 1; else hi = mid; }
        gstart[t] = lo;
    }
}

__global__ void scatter_kernel(const int* __restrict__ ei, int* __restrict__ cursor,
                               int* __restrict__ esrc) {
    int e = blockIdx.x * 256 + threadIdx.x;
    if (e >= EPE) return;
    int s, d;
    if (e < N_EDGES) { s = ei[e]; d = ei[N_EDGES + e]; }
    else { s = d = e - N_EDGES; }
    int pos = atomicAdd(&cursor[d], 1);
    esrc[pos] = s;
}

// ---------- wave-per-dst GATv2: 4 edges/iter ----------
__global__ __launch_bounds__(256) void gat_wave(
    const bf16* __restrict__ XLR, const int* __restrict__ roff, const int* __restrict__ esrc,
    const float* __restrict__ att, const float* __restrict__ gbias, bf16* __restrict__ out)
{
    const int wid = threadIdx.x >> 6;
    const int lane = threadIdx.x & 63;
    const int d = blockIdx.x * 4 + wid;
    const int beg = roff[d], end = roff[d + 1];
    const int c0 = lane * 4;

    const unsigned int* xru = (const unsigned int*)(XLR + (size_t)d * 512 + 256 + c0);
    const unsigned int xr01 = xru[0], xr23 = xru[1];
    const float xr0 = bflo(xr01), xr1 = bfhi(xr01), xr2 = bflo(xr23), xr3 = bfhi(xr23);
    const float at0 = att[c0], at1 = att[c0 + 1], at2 = att[c0 + 2], at3 = att[c0 + 3];

    float m = -INFINITY, s = 0.f;
    float a0 = 0.f, a1 = 0.f, a2 = 0.f, a3 = 0.f;

    int e = beg;
    for (; e + 3 < end; e += 4) {
        int s0 = esrc[e], s1 = esrc[e + 1], s2 = esrc[e + 2], s3 = esrc[e + 3];
        const unsigned int* q0 = (const unsigned int*)(XLR + (size_t)s0 * 512 + c0);
        const unsigned int* q1 = (const unsigned int*)(XLR + (size_t)s1 * 512 + c0);
        const unsigned int* q2 = (const unsigned int*)(XLR + (size_t)s2 * 512 + c0);
        const unsigned int* q3 = (const unsigned int*)(XLR + (size_t)s3 * 512 + c0);
        unsigned int u01 = q0[0], u23 = q0[1];
        unsigned int v01 = q1[0], v23 = q1[1];
        unsigned int w01 = q2[0], w23 = q2[1];
        unsigned int x01 = q3[0], x23 = q3[1];
        float x0 = bflo(u01), x1 = bfhi(u01), x2 = bflo(u23), x3 = bfhi(u23);
        float y0 = bflo(v01), y1 = bfhi(v01), y2 = bflo(v23), y3 = bfhi(v23);
        float z0 = bflo(w01), z1 = bfhi(w01), z2 = bflo(w23), z3 = bfhi(w23);
        float t0 = bflo(x01), t1 = bfhi(x01), t2 = bflo(x23), t3 = bfhi(x23);
        float p0 = lrelu(x0 + xr0) * at0 + lrelu(x1 + xr1) * at1
                 + lrelu(x2 + xr2) * at2 + lrelu(x3 + xr3) * at3;
        float p1 = lrelu(y0 + xr0) * at0 + lrelu(y1 + xr1) * at1
                 + lrelu(y2 + xr2) * at2 + lrelu(y3 + xr3) * at3;
        float p2 = lrelu(z0 + xr0) * at0 + lrelu(z1 + xr1) * at1
                 + lrelu(z2 + xr2) * at2 + lrelu(z3 + xr3) * at3;
        float p3 = lrelu(t0 + xr0) * at0 + lrelu(t1 + xr1) * at1
                 + lrelu(t2 + xr2) * at2 + lrelu(t3 + xr3) * at3;
        p0 += __shfl_xor(p0, 1);  p1 += __shfl_xor(p1, 1);
        p2 += __shfl_xor(p2, 1);  p3 += __shfl_xor(p3, 1);
        p0 += __shfl_xor(p0, 2);  p1 += __shfl_xor(p1, 2);
        p2 += __shfl_xor(p2, 2);  p3 += __shfl_xor(p3, 2);
        p0 += __shfl_xor(p0, 4);  p1 += __shfl_xor(p1, 4);
        p2 += __shfl_xor(p2, 4);  p3 += __shfl_xor(p3, 4);
        float mn = fmaxf(fmaxf(m, fmaxf(p0, p1)), fmaxf(p2, p3));
        float rsc = __expf(m - mn);              // first iter: exp(-inf)=0
        float w0 = __expf(p0 - mn);
        float w1 = __expf(p1 - mn);
        float w2 = __expf(p2 - mn);
        float w3 = __expf(p3 - mn);
        s = s * rsc + (w0 + w1) + (w2 + w3);
        a0 = a0 * rsc + (w0 * x0 + w1 * y0) + (w2 * z0 + w3 * t0);
        a1 = a1 * rsc + (w0 * x1 + w1 * y1) + (w2 * z1 + w3 * t1);
        a2 = a2 * rsc + (w0 * x2 + w1 * y2) + (w2 * z2 + w3 * t2);
        a3 = a3 * rsc + (w0 * x3 + w1 * y3) + (w2 * z3 + w3 * t3);
        m = mn;
    }
    for (; e < end; ++e) {                       // tail (0-3 edges)
        int s0 = esrc[e];
        const unsigned int* q0 = (const unsigned int*)(XLR + (size_t)s0 * 512 + c0);
        unsigned int u01 = q0[0], u23 = q0[1];
        float x0 = bflo(u01), x1 = bfhi(u01), x2 = bflo(u23), x3 = bfhi(u23);
        float p = lrelu(x0 + xr0) * at0 + lrelu(x1 + xr1) * at1
                + lrelu(x2 + xr2) * at2 + lrelu(x3 + xr3) * at3;
        p += __shfl_xor(p, 1);
        p += __shfl_xor(p, 2);
        p += __shfl_xor(p, 4);
        float mn = fmaxf(m, p);
        float rsc = __expf(m - mn);
        float wgt = __expf(p - mn);
        s = s * rsc + wgt;
        a0 = a0 * rsc + wgt * x0;
        a1 = a1 * rsc + wgt * x1;
        a2 = a2 * rsc + wgt * x2;
        a3 = a3 * rsc + wgt * x3;
        m = mn;
    }

    const float rinv = 1.f / (s + 1e-16f);
    float v0 = gbias[c0]     + a0 * rinv;
    float v1 = gbias[c0 + 1] + a1 * rinv;
    float v2 = gbias[c0 + 2] + a2 * rinv;
    float v3 = gbias[c0 + 3] + a3 * rinv;
    unsigned int* op = (unsigned int*)(out + (size_t)d * HID + c0);
    op[0] = bfpack(v0, v1);
    op[1] = bfpack(v2, v3);
}

// ---------- wave-per-dst GIN gather (4 gathers in flight) + zero stat ----------
__global__ __launch_bounds__(256) void gin_wave(
    const bf16* __restrict__ H, const int* __restrict__ roff,
    const int* __restrict__ esrc, bf16* __restrict__ U, float* __restrict__ stat)
{
    if (blockIdx.x == 0 && threadIdx.x == 0) { stat[0] = 0.f; stat[1] = 0.f; }
    const int wid = threadIdx.x >> 6;
    const int lane = threadIdx.x & 63;
    const int d = blockIdx.x * 4 + wid;
    const int beg = roff[d], end = roff[d + 1];
    const int c0 = lane * 4;

    float a0 = 0.f, a1 = 0.f, a2 = 0.f, a3 = 0.f;
    int e = beg;
    for (; e + 3 < end; e += 4) {
        int s0 = esrc[e], s1 = esrc[e + 1], s2 = esrc[e + 2], s3 = esrc[e + 3];
        const unsigned int* p0 = (const unsigned int*)(H + (size_t)s0 * HID + c0);
        const unsigned int* p1 = (const unsigned int*)(H + (size_t)s1 * HID + c0);
        const unsigned int* p2 = (const unsigned int*)(H + (size_t)s2 * HID + c0);
        const unsigned int* p3 = (const unsigned int*)(H + (size_t)s3 * HID + c0);
        unsigned int u01 = p0[0], u23 = p0[1];
        unsigned int v01 = p1[0], v23 = p1[1];
        unsigned int w01 = p2[0], w23 = p2[1];
        unsigned int x01 = p3[0], x23 = p3[1];
        a0 += (bflo(u01) + bflo(v01)) + (bflo(w01) + bflo(x01));
        a1 += (bfhi(u01) + bfhi(v01)) + (bfhi(w01) + bfhi(x01));
        a2 += (bflo(u23) + bflo(v23)) + (bflo(w23) + bflo(x23));
        a3 += (bfhi(u23) + bfhi(v23)) + (bfhi(w23) + bfhi(x23));
    }
    for (; e < end; ++e) {
        const unsigned int* p0 = (const unsigned int*)(H + (size_t)esrc[e] * HID + c0);
        unsigned int u01 = p0[0], u23 = p0[1];
        a0 += bflo(u01); a1 += bfhi(u01); a2 += bflo(u23); a3 += bfhi(u23);
    }
    unsigned int* up = (unsigned int*)(U + (size_t)d * HID + c0);
    up[0] = bfpack(a0, a1);
    up[1] = bfpack(a2, a3);
}

// pool softmax stats; ALSO zeroes emb[g] (emb_accum runs after in stream order)
__global__ __launch_bounds__(256) void pool_stats_kernel(
    float* __restrict__ gate, const int* __restrict__ gstart, float* __restrict__ emb)
{
    int g = blockIdx.x, t = threadIdx.x;
    emb[g * HID + t] = 0.f;
    int lo = gstart[g], hi = gstart[g + 1];
    __shared__ float red[256];
    float m = -INFINITY;
    for (int n = lo + t; n < hi; n += 256) m = fmaxf(m, gate[n]);
    red[t] = m; __syncthreads();
    for (int st = 128; st > 0; st >>= 1) { if (t < st) red[t] = fmaxf(red[t], red[t + st]); __syncthreads(); }
    m = red[0]; __syncthreads();
    float s = 0.f;
    for (int n = lo + t; n < hi; n += 256) s += __expf(gate[n] - m);
    red[t] = s; __syncthreads();
    for (int st = 128; st > 0; st >>= 1) { if (t < st) red[t] += red[t + st]; __syncthreads(); }
    float sinv = 1.f / (red[0] + 1e-16f);
    for (int n = lo + t; n < hi; n += 256) gate[n] = __expf(gate[n] - m) * sinv;
}

__global__ __launch_bounds__(256) void emb_accum_kernel(
    const float* __restrict__ a, const int* __restrict__ batch,
    const bf16* __restrict__ h, float* __restrict__ emb)
{
    int n0 = blockIdx.x * 32, t = threadIdx.x;
    int cur = batch[n0]; float acc = 0.f;
    for (int j = 0; j < 32; j++) {
        int n = n0 + j;
        int b = batch[n];
        if (b != cur) { atomicAdd(&emb[cur * HID + t], acc); cur = b; acc = 0.f; }
        acc += a[n] * (float)h[(size_t)n * HID + t];
    }
    atomicAdd(&emb[cur * HID + t], acc);
}

// ---------- label heads (R9-proven original: 512 blocks) ----------
__global__ __launch_bounds__(256) void heads_kernel(
    const float* __restrict__ emb, const float* __restrict__ W1, const float* __restrict__ b1,
    const float* __restrict__ hg, const float* __restrict__ hbe, const float* __restrict__ W2,
    const float* __restrict__ b2, float* __restrict__ out)
{
    int o = blockIdx.x;
    int g0 = blockIdx.y * 4;
    int k = threadIdx.x;
    __shared__ float se[4][HID];
    __shared__ float red[256];
#pragma unroll
    for (int j = 0; j < 4; j++) se[j][k] = emb[(g0 + j) * HID + k];
    __syncthreads();
    const float* w1p = W1 + (size_t)o * HID * HID + k;
    float zb = b1[o * HID + k];
    float z0 = zb, z1 = zb, z2 = zb, z3 = zb;
#pragma unroll 8
    for (int d = 0; d < HID; d++) {
        float w = w1p[(size_t)d * HID];
        z0 = fmaf(se[0][d], w, z0);
        z1 = fmaf(se[1][d], w, z1);
        z2 = fmaf(se[2][d], w, z2);
        z3 = fmaf(se[3][d], w, z3);
    }
    const float gk = hg[o * HID + k] * rsqrtf(1.f + EPSC);
    const float bek = hbe[o * HID + k];
    const float w2 = W2[o * HID + k];
    const float b2o = b2[o];
    float zz[4] = {z0, z1, z2, z3};
#pragma unroll
    for (int j = 0; j < 4; j++) {
        float z = zz[j];
        float sil = z / (1.f + expf(-z));
        red[k] = (sil * gk + bek) * w2;
        __syncthreads();
        for (int st = 128; st > 0; st >>= 1) { if (k < st) red[k] += red[k + st]; __syncthreads(); }
        if (k == 0) out[(g0 + j) * NO + o] = red[0] + b2o;
        __syncthreads();
    }
}

extern "C" void kernel_launch(void* const* d_in, const int* in_sizes, int n_in,
                              void* d_out, int out_size, void* d_ws, size_t ws_size,
                              hipStream_t stream) {
    const float* x        = (const float*)d_in[0];
    const int*   ei       = (const int*)  d_in[1];
    const int*   batch    = (const int*)  d_in[2];
    const float* fp_W     = (const float*)d_in[3];
    const float* fp_b     = (const float*)d_in[4];
    const float* fp_g     = (const float*)d_in[5];
    const float* fp_be    = (const float*)d_in[6];
    const float* gat_Wl   = (const float*)d_in[7];
    const float* gat_bl   = (const float*)d_in[8];
    const float* gat_Wr   = (const float*)d_in[9];
    const float* gat_br   = (const float*)d_in[10];
    const float* gat_att  = (const float*)d_in[11];
    const float* gat_bias = (const float*)d_in[12];
    const float* gin_W    = (const float*)d_in[13];
    const float* gin_b    = (const float*)d_in[14];
    const float* gin_g    = (const float*)d_in[15];
    const float* gin_be   = (const float*)d_in[16];
    const float* ln_g     = (const float*)d_in[17];
    const float* ln_b     = (const float*)d_in[18];
    const float* res_W    = (const float*)d_in[19];
    const float* res_b    = (const float*)d_in[20];
    const float* pool_W1  = (const float*)d_in[21];
    const float* pool_b1  = (const float*)d_in[22];
    const float* pool_W2  = (const float*)d_in[23];
    const float* pool_b2  = (const float*)d_in[24];
    const float* head_W1  = (const float*)d_in[25];
    const float* head_b1  = (const float*)d_in[26];
    const float* head_g   = (const float*)d_in[27];
    const float* head_be  = (const float*)d_in[28];
    const float* head_W2  = (const float*)d_in[29];
    const float* head_b2  = (const float*)d_in[30];
    float* out = (float*)d_out;

    char* base = (char*)d_ws;
    size_t off = 0;
    auto alloc = [&](size_t bytes) -> char* {
        char* p = base + off; off += (bytes + 255) & ~(size_t)255; return p;
    };
    int*   esrc   = (int*)  alloc((size_t)EPE * 4);
    int*   cnt    = (int*)  alloc((size_t)N_NODES * 4);
    int*   roff   = (int*)  alloc((size_t)(N_NODES + 1) * 4);
    int*   cursor = (int*)  alloc((size_t)N_NODES * 4);
    float* gate   = (float*)alloc((size_t)N_NODES * 4);
    int*   gstart = (int*)  alloc((NG + 1) * 4);
    float* emb    = (float*)alloc(NG * HID * 4);
    float* stat   = (float*)alloc(8);
    bf16*  Hb0    = (bf16*) alloc((size_t)N_NODES * HID * 2);
    bf16*  Hb1    = (bf16*) alloc((size_t)N_NODES * HID * 2);
    bf16*  XLR    = (bf16*) alloc((size_t)N_NODES * 512 * 2);
    bf16*  fpWt   = (bf16*) alloc((size_t)DIN * HID * 2);
    bf16*  wlrT0  = (bf16*) alloc((size_t)512 * HID * 2);
    bf16*  wlrT1  = (bf16*) alloc((size_t)512 * HID * 2);
    bf16*  gwT    = (bf16*) alloc((size_t)2 * HID * HID * 2);
    bf16*  rwT    = (bf16*) alloc((size_t)2 * HID * HID * 2);
    bf16*  pwT    = (bf16*) alloc((size_t)HID * HID * 2);
    bf16*  Ub     = XLR;
    bf16*  wlrT[2] = { wlrT0, wlrT1 };

    // ---- fused weight conversion + cnt/gate zeroing (1 launch) ----
    wconv_all<<<3584, 256, 0, stream>>>(fp_W, gat_Wl, gat_Wr, gin_W, res_W, pool_W1,
                                        fpWt, wlrT0, wlrT1, gwT, rwT, pwT, cnt, gate);

    // ---- CSR build (+ graph boundaries fused into scan) ----
    hist_kernel<<<(EPE + 255) / 256, 256, 0, stream>>>(ei, cnt);
    scan_kernel<<<1, 1024, 0, stream>>>(cnt, roff, cursor, batch, gstart);
    scatter_kernel<<<(EPE + 255) / 256, 256, 0, stream>>>(ei, cursor, esrc);

    // ---- feature projection (128x128 tiles, depth-4, champion config) ----
    dim3 gridF(2, 125);
    dim3 g128_256(2, 125);       // 128x128 tiles, 256 cols
    dim3 g128_512(4, 125);       // 128x128 tiles, 512 cols
    gemm_f32A<<<gridF, 256, 0, stream>>>(x, fpWt, fp_b, Hb0, DIN, fp_g, fp_be);

    bf16* hcur = Hb0;
    bf16* hoth = Hb1;
    for (int i = 0; i < 2; i++) {
        // xl|xr
        gemm128<<<g128_512, 256, 0, stream>>>(hcur, wlrT[i], gat_bl + i * HID, gat_br + i * HID,
                                              XLR, HID, 512, 0, nullptr, nullptr, nullptr);
        // GAT -> hoth (wave-per-dst, 4 edges/iter)
        gat_wave<<<N_NODES / 4, 256, 0, stream>>>(XLR, roff, esrc, gat_att + i * HEADS * CPH,
                                                  gat_bias + i * HID, hoth);
        // GIN aggregate -> Ub (wave-per-dst, 4 gathers/iter), zeroes stat
        gin_wave<<<N_NODES / 4, 256, 0, stream>>>(hoth, roff, esrc, Ub, stat);
        // h_gin = leaky(BN(relu(u@W+b))) -> hcur, stats atomically into stat
        gemm128<<<g128_256, 256, 0, stream>>>(Ub, gwT + (size_t)i * HID * HID, gin_b + i * HID,
                                              nullptr, hcur, HID, HID, 2,
                                              gin_g + i * HID, gin_be + i * HID, stat);
        // h = leaky(LN(h_gin) + h_gin@res_W + res_b) -> hoth
        gemm128<<<g128_256, 256, 0, stream>>>(hcur, rwT + (size_t)i * HID * HID, res_b + i * HID,
                                              nullptr, hoth, HID, HID, 3,
                                              ln_g + i * HID, ln_b + i * HID, stat);
        bf16* tmp = hcur; hcur = hoth; hoth = tmp;
    }

    // ---- global attention pooling: gate fused into GEMM epilogue (mode 4) ----
    gemm128<<<g128_256, 256, 0, stream>>>(hcur, pwT, pool_b1, nullptr, nullptr, HID, HID, 4,
                                          pool_W2, nullptr, gate);
    pool_stats_kernel<<<NG, 256, 0, stream>>>(gate, gstart, emb);
    emb_accum_kernel<<<N_NODES / 32, 256, 0, stream>>>(gate, batch, hcur, emb);

    // ---- label heads (R9-proven original) ----
    dim3 hgrid(NO, 8);
    heads_kernel<<<hgrid, 256, 0, stream>>>(emb, head_W1, head_b1, head_g, head_be,
                                            head_W2, head_b2, out);
}